// Round 2
// baseline (972.911 us; speedup 1.0000x reference)
//
#include <hip/hip_runtime.h>
#include <hip/hip_bf16.h>
#include <stdint.h>

// MobileViTBlockV2: B=16, C=256, H=W=64, D=256, F=512, L=2, patch 2x2.
// Channels-last bf16 activations, fp32 residual, MFMA bf16 GEMMs.
// R2: global_load_lds (16B) staging with [seg][row][8] LDS layout (DMA-order,
// 2-way-max banks), LDS-staged coalesced epilogue.

#define B_    16
#define C_    256
#define D_    256
#define F_    512
#define NPIX  4096
#define NE_PB 1048576   // D_*NPIX elements per batch for GN

typedef __attribute__((ext_vector_type(8))) short  short8;
typedef __attribute__((ext_vector_type(4))) short  short4v;
typedef __attribute__((ext_vector_type(4))) float  f32x4;

__device__ __forceinline__ float b2f(short s){
  return __uint_as_float(((unsigned)(unsigned short)s) << 16);
}
__device__ __forceinline__ short f2b(float f){
  unsigned u = __float_as_uint(f);
  return (short)((u + 0x7fffu + ((u >> 16) & 1u)) >> 16);  // RNE
}
__device__ __forceinline__ float silu_f(float x){ return x / (1.f + expf(-x)); }

__device__ __forceinline__ void gld16(const short* g, short* l){
  __builtin_amdgcn_global_load_lds(
      (const __attribute__((address_space(1))) void*)g,
      (__attribute__((address_space(3))) void*)l, 16, 0, 0);
}

// ---------- small prep kernels ----------
__global__ void cvt_k(const float* __restrict__ s, short* __restrict__ d, int n){
  int i = blockIdx.x*256 + threadIdx.x;
  if (i < n) d[i] = f2b(s[i]);
}
__global__ void zero_k(float* __restrict__ p, int n){
  int i = blockIdx.x*256 + threadIdx.x;
  if (i < n) p[i] = 0.f;
}

// ---------- dwconv3x3 + BN + SiLU (channel-major in, channel-major bf16 out) ----------
__global__ void dwconv_k(const float* __restrict__ X, const float* __restrict__ W,
                         const float* __restrict__ G, const float* __restrict__ Bb,
                         const float* __restrict__ Mn, const float* __restrict__ Vr,
                         short* __restrict__ O){
  const int h0 = blockIdx.x * 8;
  const int c  = blockIdx.y;
  const int b  = blockIdx.z;
  const int t  = threadIdx.x;
  __shared__ float xs[10][66];
  const float* xp = X + ((size_t)(b*C_ + c)) * NPIX;
  for (int i = t; i < 660; i += 256){
    int r = i / 66, col = i - r*66;
    int h = h0 - 1 + r, w = col - 1;
    float v = 0.f;
    if (h >= 0 && h < 64 && w >= 0 && w < 64) v = xp[h*64 + w];
    xs[r][col] = v;
  }
  __syncthreads();
  float wgt[9];
#pragma unroll
  for (int j = 0; j < 9; ++j) wgt[j] = W[c*9 + j];
  const float scale = G[c] * rsqrtf(Vr[c] + 1e-5f);
  const float mu = Mn[c], bb = Bb[c];
  short* op = O + ((size_t)(b*C_ + c)) * NPIX;
  for (int i = t; i < 512; i += 256){
    int r = i >> 6, w = i & 63;
    float s = 0.f;
#pragma unroll
    for (int dh = 0; dh < 3; ++dh)
#pragma unroll
      for (int dw = 0; dw < 3; ++dw)
        s += xs[r+dh][w+dw] * wgt[dh*3+dw];
    float y = (s - mu) * scale + bb;
    y = silu_f(y);
    op[(h0 + r)*64 + w] = f2b(y);
  }
}

// ---------- (b,c,s) -> (b,s,c) bf16 transpose ----------
__global__ void transpose_k(const short* __restrict__ I, short* __restrict__ O){
  const int s0 = blockIdx.x*32, c0 = blockIdx.y*32, b = blockIdx.z;
  const int tx = threadIdx.x & 31, ty = threadIdx.x >> 5;
  __shared__ short tile[32][33];
#pragma unroll
  for (int j = 0; j < 4; ++j)
    tile[ty + 8*j][tx] = I[((size_t)(b*C_ + c0 + ty + 8*j))*NPIX + s0 + tx];
  __syncthreads();
#pragma unroll
  for (int j = 0; j < 4; ++j)
    O[((size_t)(b*NPIX + s0 + ty + 8*j))*C_ + c0 + tx] = tile[tx][ty + 8*j];
}

// ---------- MFMA bf16 GEMM: out[m,n] = sum_k Wt[m,k]*X[n,k], 128x128 tile ----------
// EPI: 0 = write f32 P (no bias); 1 = +bias -> bf16 Obf; 2 = P += acc+bias;
//      3 = silu(acc+bias) -> bf16 Obf; 4 = BN(acc) -> f32 channel-major Of32
template<int EPI>
__global__ __launch_bounds__(256)
void gemm_k(const short* __restrict__ A, const short* __restrict__ X,
            const int M, const int K,
            const float* __restrict__ bias,
            float* __restrict__ P,
            short* __restrict__ Obf,
            float* __restrict__ Of32,
            const float* __restrict__ bng, const float* __restrict__ bnb,
            const float* __restrict__ bnm, const float* __restrict__ bnv)
{
  const int nt = blockIdx.x, mt = blockIdx.y, b = blockIdx.z;
  const int tid  = threadIdx.x;
  const int ln = tid & 63, wv = tid >> 6;
  const int wm = (wv >> 1)*64, wn = (wv & 1)*64;
  const int wg = wv >> 1;
  const int lr = ln & 15, lq = ln >> 4;

  // smem: staging As/Bs (8KB each, layout [seg4][row128][8elem]) reused as
  // epilogue CT (128x68 f32 pix-major, or 64x132 f32 chan-major for EPI=4)
  __shared__ __align__(16) char smem[34816];
  short* As = (short*)smem;
  short* Bs = As + 4096;
  float* CT = (float*)smem;

  const short* Ap = A + (size_t)mt*128*K;
  const short* Xp = X + ((size_t)b*NPIX + (size_t)nt*128) * K;

  // staging descriptors: wave wv handles chunks wv and wv+4 of each 8KB tile.
  // chunk blk covers seg=blk>>1, rows ((blk&1)*64 .. +63); lane ln -> row.
  const int stg_row = ((wv & 1) << 6) | ln;
  const int stg_off = (wv >> 1) * 8;            // k-element offset (seg*8)
  const short* gA = Ap + (size_t)stg_row * K + stg_off;
  const short* gB = Xp + (size_t)stg_row * K + stg_off;
  short* lA0 = As + wv * 512;
  short* lA1 = As + (wv + 4) * 512;
  short* lB0 = Bs + wv * 512;
  short* lB1 = Bs + (wv + 4) * 512;

  f32x4 acc[4][4];
#pragma unroll
  for (int r = 0; r < 4; ++r)
#pragma unroll
    for (int c = 0; c < 4; ++c) acc[r][c] = (f32x4){0.f,0.f,0.f,0.f};

  for (int k0 = 0; k0 < K; k0 += 32){
    gld16(gA + k0,      lA0);
    gld16(gA + k0 + 16, lA1);
    gld16(gB + k0,      lB0);
    gld16(gB + k0 + 16, lB1);
    __syncthreads();
    short8 af[4], bfr[4];
#pragma unroll
    for (int r = 0; r < 4; ++r) af[r]  = *(const short8*)&As[lq*1024 + (wm + r*16 + lr)*8];
#pragma unroll
    for (int c = 0; c < 4; ++c) bfr[c] = *(const short8*)&Bs[lq*1024 + (wn + c*16 + lr)*8];
#pragma unroll
    for (int r = 0; r < 4; ++r)
#pragma unroll
      for (int c = 0; c < 4; ++c)
        acc[r][c] = __builtin_amdgcn_mfma_f32_16x16x32_bf16(af[r], bfr[c], acc[r][c], 0, 0, 0);
    __syncthreads();
  }

  // ---- LDS-staged epilogue: 2 passes over r-pairs ----
#pragma unroll
  for (int p = 0; p < 2; ++p){
    if (p) __syncthreads();
    // write phase
    if constexpr (EPI != 4){
#pragma unroll
      for (int rr = 0; rr < 2; ++rr){
        const int r = 2*p + rr;
        const int col = wg*32 + rr*16 + lq*4;
        f32x4 bv = (f32x4){0.f,0.f,0.f,0.f};
        if constexpr (EPI == 1 || EPI == 2 || EPI == 3)
          bv = *(const f32x4*)&bias[mt*128 + wm + r*16 + lq*4];
#pragma unroll
        for (int c = 0; c < 4; ++c){
          const int n = wn + c*16 + lr;
          f32x4 v = acc[r][c];
          v.x += bv.x; v.y += bv.y; v.z += bv.z; v.w += bv.w;
          *(f32x4*)&CT[n*68 + col] = v;
        }
      }
    } else {
      // channel-major CT2[64 cols][132]
#pragma unroll
      for (int rr = 0; rr < 2; ++rr){
        const int r = 2*p + rr;
        const int col = wg*32 + rr*16 + lq*4;
#pragma unroll
        for (int c = 0; c < 4; ++c){
          const int n = wn + c*16 + lr;
          f32x4 v = acc[r][c];
          CT[(col+0)*132 + n] = v.x;
          CT[(col+1)*132 + n] = v.y;
          CT[(col+2)*132 + n] = v.z;
          CT[(col+3)*132 + n] = v.w;
        }
      }
    }
    __syncthreads();
    // store phase
    if constexpr (EPI == 0 || EPI == 2){
#pragma unroll
      for (int it = 0; it < 8; ++it){
        const int ck = it*256 + tid;            // 0..2047
        const int rw = ck >> 4, cb = (ck & 15)*4;
        const int chan = mt*128 + ((cb >> 5) << 6) + p*32 + (cb & 31);
        const size_t pixg = (size_t)b*NPIX + (size_t)nt*128 + rw;
        f32x4 v = *(const f32x4*)&CT[rw*68 + cb];
        float* dst = &P[pixg*(size_t)M + chan];
        if constexpr (EPI == 2){
          f32x4 o = *(const f32x4*)dst;
          v.x += o.x; v.y += o.y; v.z += o.z; v.w += o.w;
        }
        *(f32x4*)dst = v;
      }
    } else if constexpr (EPI == 1 || EPI == 3){
#pragma unroll
      for (int it = 0; it < 8; ++it){
        const int ck = it*256 + tid;
        const int rw = ck >> 4, cb = (ck & 15)*4;
        const int chan = mt*128 + ((cb >> 5) << 6) + p*32 + (cb & 31);
        const size_t pixg = (size_t)b*NPIX + (size_t)nt*128 + rw;
        f32x4 v = *(const f32x4*)&CT[rw*68 + cb];
        if constexpr (EPI == 3){
          v.x = silu_f(v.x); v.y = silu_f(v.y); v.z = silu_f(v.z); v.w = silu_f(v.w);
        }
        short4v o;
        o.x = f2b(v.x); o.y = f2b(v.y); o.z = f2b(v.z); o.w = f2b(v.w);
        *(short4v*)&Obf[pixg*(size_t)M + chan] = o;
      }
    } else {  // EPI == 4: BN, channel-major f32 out
#pragma unroll
      for (int it = 0; it < 8; ++it){
        const int ck = it*256 + tid;            // 64 rows x 32 chunks
        const int rw = ck >> 5, cb = (ck & 31)*4;
        const int chan = mt*128 + ((rw >> 5) << 6) + p*32 + (rw & 31);
        f32x4 v = *(const f32x4*)&CT[rw*132 + cb];
        const float sc = bng[chan] * rsqrtf(bnv[chan] + 1e-5f);
        const float mu = bnm[chan], bb = bnb[chan];
        f32x4 o;
        o.x = (v.x - mu)*sc + bb; o.y = (v.y - mu)*sc + bb;
        o.z = (v.z - mu)*sc + bb; o.w = (v.w - mu)*sc + bb;
        *(f32x4*)&Of32[((size_t)(b*C_ + chan))*NPIX + (size_t)nt*128 + cb] = o;
      }
    }
  }
}

// ---------- GN (1 group = layernorm over D*P*N per batch): stats then apply ----------
__global__ void gn_stats_k(const float* __restrict__ P, float* __restrict__ st){
  const int b = blockIdx.y;
  const size_t base = (size_t)b*NE_PB + (size_t)blockIdx.x*16384 + threadIdx.x*4;
  float sm = 0.f, ss = 0.f;
#pragma unroll
  for (int i = 0; i < 16; ++i){
    f32x4 v = *(const f32x4*)&P[base + (size_t)i*1024];
    sm += v.x + v.y + v.z + v.w;
    ss += v.x*v.x + v.y*v.y + v.z*v.z + v.w*v.w;
  }
#pragma unroll
  for (int o = 32; o > 0; o >>= 1){ sm += __shfl_down(sm, o); ss += __shfl_down(ss, o); }
  __shared__ float r1[4], r2[4];
  const int lane = threadIdx.x & 63, wv = threadIdx.x >> 6;
  if (lane == 0){ r1[wv] = sm; r2[wv] = ss; }
  __syncthreads();
  if (threadIdx.x == 0){
    atomicAdd(&st[b*2+0], r1[0]+r1[1]+r1[2]+r1[3]);
    atomicAdd(&st[b*2+1], r2[0]+r2[1]+r2[2]+r2[3]);
  }
}

__global__ void gn_apply_k(const float* __restrict__ P, const float* __restrict__ st,
                           const float* __restrict__ G, const float* __restrict__ Bb,
                           short* __restrict__ U){
  const int b = blockIdx.y;
  const float mean = st[b*2]   * (1.f/NE_PB);
  const float var  = st[b*2+1] * (1.f/NE_PB) - mean*mean;
  const float inv  = rsqrtf(var + 1e-5f);
  const int c0 = (threadIdx.x*4) & 255;
  const f32x4 g4 = *(const f32x4*)&G[c0];
  const f32x4 b4 = *(const f32x4*)&Bb[c0];
  const size_t base = (size_t)b*NE_PB + (size_t)blockIdx.x*16384 + threadIdx.x*4;
#pragma unroll
  for (int i = 0; i < 16; ++i){
    f32x4 v = *(const f32x4*)&P[base + (size_t)i*1024];
    short4v o;
    o.x = f2b((v.x - mean)*inv*g4.x + b4.x);
    o.y = f2b((v.y - mean)*inv*g4.y + b4.y);
    o.z = f2b((v.z - mean)*inv*g4.z + b4.z);
    o.w = f2b((v.w - mean)*inv*g4.w + b4.w);
    *(short4v*)&U[base + (size_t)i*1024] = o;
  }
}

// ---------- q = Wq . u + qb  (one wave per pixel) ----------
__global__ void q_k(const short* __restrict__ U, const float* __restrict__ Wq,
                    const float* __restrict__ Qb, float* __restrict__ Q){
  const int lane = threadIdx.x & 63;
  const int pix = (blockIdx.x*256 + threadIdx.x) >> 6;  // global pixel 0..65535
  short4v u4 = *(const short4v*)&U[(size_t)pix*256 + lane*4];
  f32x4  w4 = *(const f32x4*)&Wq[lane*4];
  float s = b2f(u4.x)*w4.x + b2f(u4.y)*w4.y + b2f(u4.z)*w4.z + b2f(u4.w)*w4.w;
#pragma unroll
  for (int o = 32; o > 0; o >>= 1) s += __shfl_down(s, o);
  if (lane == 0) Q[pix] = s + Qb[0];
}

// ---------- softmax over the 1024 pixels of one parity class ----------
__global__ void softmax_k(const float* __restrict__ Q, float* __restrict__ S){
  const int bp = blockIdx.x, b = bp >> 2, p = bp & 3;
  const int ph = p >> 1, pw = p & 1;
  const int t = threadIdx.x;
  float vals[4]; int ns[4];
  float mx = -1e30f;
#pragma unroll
  for (int j = 0; j < 4; ++j){
    int n = t + j*256;
    int h = 2*(n >> 5) + ph, w = 2*(n & 31) + pw;
    float q = Q[b*NPIX + h*64 + w];
    vals[j] = q; ns[j] = n;
    mx = fmaxf(mx, q);
  }
  __shared__ float red[4];
  const int lane = t & 63, wv = t >> 6;
#pragma unroll
  for (int o = 32; o > 0; o >>= 1) mx = fmaxf(mx, __shfl_down(mx, o));
  if (lane == 0) red[wv] = mx;
  __syncthreads();
  mx = fmaxf(fmaxf(red[0], red[1]), fmaxf(red[2], red[3]));
  __syncthreads();
  float sum = 0.f;
#pragma unroll
  for (int j = 0; j < 4; ++j){ vals[j] = expf(vals[j] - mx); sum += vals[j]; }
#pragma unroll
  for (int o = 32; o > 0; o >>= 1) sum += __shfl_down(sum, o);
  if (lane == 0) red[wv] = sum;
  __syncthreads();
  sum = red[0] + red[1] + red[2] + red[3];
  const float r = 1.f / sum;
#pragma unroll
  for (int j = 0; j < 4; ++j) S[bp*1024 + ns[j]] = vals[j]*r;
}

// ---------- ctx partial: ctx[b,p,c] = sum_n k[b,pix(p,n),c]*s[b,p,n] (8 chunks) ----------
__global__ void ctx_k(const short* __restrict__ KV, const float* __restrict__ S,
                      float* __restrict__ CP){
  const int bp = blockIdx.x, chunk = blockIdx.y;
  const int b = bp >> 2, p = bp & 3;
  const int ph = p >> 1, pw = p & 1;
  const int c = threadIdx.x;
  __shared__ float sl[128];
  const int n0 = chunk*128;
  if (c < 128) sl[c] = S[bp*1024 + n0 + c];
  __syncthreads();
  float acc = 0.f;
  for (int j = 0; j < 128; ++j){
    int n = n0 + j;
    int h = 2*(n >> 5) + ph, w = 2*(n & 31) + pw;
    acc += b2f(KV[((size_t)(b*NPIX) + h*64 + w)*512 + c]) * sl[j];
  }
  CP[(size_t)(bp*8 + chunk)*256 + c] = acc;
}

__global__ void ctx_sum_k(const float* __restrict__ CP, float* __restrict__ CT){
  const int bp = blockIdx.x, c = threadIdx.x;
  float s = 0.f;
#pragma unroll
  for (int j = 0; j < 8; ++j) s += CP[(size_t)(bp*8 + j)*256 + c];
  CT[bp*256 + c] = s;
}

// ---------- attn input: relu(v) * ctx[parity] -> bf16 channels-last ----------
__global__ void attn_in_k(const short* __restrict__ KV, const float* __restrict__ CT,
                          short* __restrict__ O){
  const size_t vid = (size_t)blockIdx.x*256 + threadIdx.x;  // 4-channel vectors
  const int c4  = (int)(vid & 63);
  const int pix = (int)((vid >> 6) & 4095);
  const int b   = (int)(vid >> 18);
  const int h = pix >> 6, w = pix & 63;
  const int par = (h & 1)*2 + (w & 1);
  short4v v4 = *(const short4v*)&KV[((size_t)(b*NPIX) + pix)*512 + 256 + c4*4];
  f32x4  cx = *(const f32x4*)&CT[(b*4 + par)*256 + c4*4];
  short4v o;
  o.x = f2b(fmaxf(b2f(v4.x), 0.f)*cx.x);
  o.y = f2b(fmaxf(b2f(v4.y), 0.f)*cx.y);
  o.z = f2b(fmaxf(b2f(v4.z), 0.f)*cx.z);
  o.w = f2b(fmaxf(b2f(v4.w), 0.f)*cx.w);
  *(short4v*)&O[((size_t)(b*NPIX) + pix)*256 + c4*4] = o;
}

extern "C" void kernel_launch(void* const* d_in, const int* in_sizes, int n_in,
                              void* d_out, int out_size, void* d_ws, size_t ws_size,
                              hipStream_t stream){
  const float* x      = (const float*)d_in[0];
  const float* dw_w   = (const float*)d_in[1];
  const float* dw_g   = (const float*)d_in[2];
  const float* dw_b   = (const float*)d_in[3];
  const float* dw_m   = (const float*)d_in[4];
  const float* dw_v   = (const float*)d_in[5];
  const float* pw_w   = (const float*)d_in[6];
  const float* gn1_g  = (const float*)d_in[7];
  const float* gn1_b  = (const float*)d_in[8];
  const float* qkv_w  = (const float*)d_in[9];
  const float* qkv_b  = (const float*)d_in[10];
  const float* out_w  = (const float*)d_in[11];
  const float* out_b  = (const float*)d_in[12];
  const float* gn2_g  = (const float*)d_in[13];
  const float* gn2_b  = (const float*)d_in[14];
  const float* ffn1_w = (const float*)d_in[15];
  const float* ffn1_b = (const float*)d_in[16];
  const float* ffn2_w = (const float*)d_in[17];
  const float* ffn2_b = (const float*)d_in[18];
  const float* gnf_g  = (const float*)d_in[19];
  const float* gnf_b  = (const float*)d_in[20];
  const float* proj_w = (const float*)d_in[21];
  const float* pbn_g  = (const float*)d_in[22];
  const float* pbn_b  = (const float*)d_in[23];
  const float* pbn_m  = (const float*)d_in[24];
  const float* pbn_v  = (const float*)d_in[25];
  float* out = (float*)d_out;

  uint8_t* w8 = (uint8_t*)d_ws;
  float* P     = (float*)(w8);                 // fp32 residual, 64 MiB
  short* bufA  = (short*)(w8 + 67108864);      // bf16 (B,4096,256), 32 MiB
  short* bufB  = (short*)(w8 + 100663296);     // bf16 (B,4096,512), 64 MiB
  short* w_pw  = (short*)(w8 + 167772160);
  short* w_qkv = (short*)(w8 + 167903232);
  short* w_out = (short*)(w8 + 168428544);
  short* w_f1  = (short*)(w8 + 168690688);
  short* w_f2  = (short*)(w8 + 169214976);
  short* w_pj  = (short*)(w8 + 169739264);
  float* qbuf  = (float*)(w8 + 169870336);     // (B*4096)
  float* scor  = (float*)(w8 + 170132480);     // (64,1024)
  float* ctxp  = (float*)(w8 + 170394624);     // (64,8,256)
  float* ctxs  = (float*)(w8 + 170918912);     // (64,256)
  float* stats = (float*)(w8 + 170984448);     // 5 sites x 16 x 2

  // weight casts + stat zeroing (runs every call; cheap)
  cvt_k<<<256, 256, 0, stream>>>(pw_w,   w_pw,  65536);
  cvt_k<<<1027, 256, 0, stream>>>(qkv_w, w_qkv, 262656);
  cvt_k<<<512, 256, 0, stream>>>(out_w,  w_out, 131072);
  cvt_k<<<1024, 256, 0, stream>>>(ffn1_w, w_f1, 262144);
  cvt_k<<<1024, 256, 0, stream>>>(ffn2_w, w_f2, 262144);
  cvt_k<<<256, 256, 0, stream>>>(proj_w, w_pj,  65536);
  zero_k<<<1, 256, 0, stream>>>(stats, 160);

  dwconv_k<<<dim3(8,256,16), 256, 0, stream>>>(x, dw_w, dw_g, dw_b, dw_m, dw_v, bufB);
  transpose_k<<<dim3(128,8,16), 256, 0, stream>>>(bufB, bufA);
  // pw conv -> fp32 residual P
  gemm_k<0><<<dim3(32,2,16), 256, 0, stream>>>(w_pw, bufA, 256, 256, nullptr, P,
                                               nullptr, nullptr, nullptr, nullptr, nullptr, nullptr);

  for (int i = 0; i < 2; ++i){
    float* st1 = stats + (2*i)*32;
    gn_stats_k<<<dim3(64,16), 256, 0, stream>>>(P, st1);
    gn_apply_k<<<dim3(64,16), 256, 0, stream>>>(P, st1, gn1_g + i*256, gn1_b + i*256, bufA);
    q_k<<<16384, 256, 0, stream>>>(bufA, qkv_w + i*513*256, qkv_b + i*513, qbuf);
    gemm_k<1><<<dim3(32,4,16), 256, 0, stream>>>(w_qkv + (i*513+1)*256, bufA, 512, 256,
                                                 qkv_b + i*513 + 1, nullptr, bufB, nullptr,
                                                 nullptr, nullptr, nullptr, nullptr);
    softmax_k<<<64, 256, 0, stream>>>(qbuf, scor);
    ctx_k<<<dim3(64,8), 256, 0, stream>>>(bufB, scor, ctxp);
    ctx_sum_k<<<64, 256, 0, stream>>>(ctxp, ctxs);
    attn_in_k<<<16384, 256, 0, stream>>>(bufB, ctxs, bufA);
    gemm_k<2><<<dim3(32,2,16), 256, 0, stream>>>(w_out + i*65536, bufA, 256, 256,
                                                 out_b + i*256, P, nullptr, nullptr,
                                                 nullptr, nullptr, nullptr, nullptr);
    float* st2 = stats + (2*i+1)*32;
    gn_stats_k<<<dim3(64,16), 256, 0, stream>>>(P, st2);
    gn_apply_k<<<dim3(64,16), 256, 0, stream>>>(P, st2, gn2_g + i*256, gn2_b + i*256, bufA);
    gemm_k<3><<<dim3(32,4,16), 256, 0, stream>>>(w_f1 + i*131072, bufA, 512, 256,
                                                 ffn1_b + i*512, nullptr, bufB, nullptr,
                                                 nullptr, nullptr, nullptr, nullptr);
    gemm_k<2><<<dim3(32,2,16), 256, 0, stream>>>(w_f2 + i*131072, bufB, 256, 512,
                                                 ffn2_b + i*256, P, nullptr, nullptr,
                                                 nullptr, nullptr, nullptr, nullptr);
  }

  float* st = stats + 4*32;
  gn_stats_k<<<dim3(64,16), 256, 0, stream>>>(P, st);
  gn_apply_k<<<dim3(64,16), 256, 0, stream>>>(P, st, gnf_g, gnf_b, bufA);
  gemm_k<4><<<dim3(32,2,16), 256, 0, stream>>>(w_pj, bufA, 256, 256, nullptr,
                                               nullptr, nullptr, out,
                                               pbn_g, pbn_b, pbn_m, pbn_v);

  (void)in_sizes; (void)n_in; (void)out_size; (void)ws_size;
}

// Round 3
// 861.225 us; speedup vs baseline: 1.1297x; 1.1297x over previous
//
#include <hip/hip_runtime.h>
#include <hip/hip_bf16.h>
#include <stdint.h>

// MobileViTBlockV2: B=16, C=256, H=W=64, D=256, F=512, L=2, patch 2x2.
// R3: X-as-A MFMA GEMM (pixel on reg axis -> coalesced epilogue), BK=64,
// XOR-swizzled LDS, fused GN stats, parity-permuted attention path.

#define B_    16
#define C_    256
#define D_    256
#define NPIX  4096
#define NE_PB 1048576   // D_*NPIX elements per batch for GN

typedef __attribute__((ext_vector_type(8))) short  short8;
typedef __attribute__((ext_vector_type(4))) short  short4v;
typedef __attribute__((ext_vector_type(4))) float  f32x4;

__device__ __forceinline__ float b2f(short s){
  return __uint_as_float(((unsigned)(unsigned short)s) << 16);
}
__device__ __forceinline__ short f2b(float f){
  unsigned u = __float_as_uint(f);
  return (short)((u + 0x7fffu + ((u >> 16) & 1u)) >> 16);  // RNE
}
__device__ __forceinline__ float silu_f(float x){ return x / (1.f + expf(-x)); }

__device__ __forceinline__ void gld16(const short* g, short* l){
  __builtin_amdgcn_global_load_lds(
      (const __attribute__((address_space(1))) void*)g,
      (__attribute__((address_space(3))) void*)l, 16, 0, 0);
}

// pixel -> parity-permuted index: pi = parity*1024 + (h/2)*32 + (w/2)
__device__ __forceinline__ int pix2pi(int pix){
  int h = pix >> 6, w = pix & 63;
  return ((h & 1)*2 + (w & 1))*1024 + (h >> 1)*32 + (w >> 1);
}
// inverse
__device__ __forceinline__ int pi2pix(int n){
  int p = n >> 10, idx = n & 1023;
  int h = ((idx >> 5) << 1) | (p >> 1);
  int w = ((idx & 31) << 1) | (p & 1);
  return h*64 + w;
}

// ---------- small prep kernels ----------
__global__ void cvt_k(const float* __restrict__ s, short* __restrict__ d, int n){
  int i = blockIdx.x*256 + threadIdx.x;
  if (i < n) d[i] = f2b(s[i]);
}
__global__ void zero_k(float* __restrict__ p, int n){
  int i = blockIdx.x*256 + threadIdx.x;
  if (i < n) p[i] = 0.f;
}

// ---------- dwconv3x3 + BN + SiLU (channel-major in, channel-major bf16 out) ----------
__global__ void dwconv_k(const float* __restrict__ X, const float* __restrict__ W,
                         const float* __restrict__ G, const float* __restrict__ Bb,
                         const float* __restrict__ Mn, const float* __restrict__ Vr,
                         short* __restrict__ O){
  const int h0 = blockIdx.x * 8;
  const int c  = blockIdx.y;
  const int b  = blockIdx.z;
  const int t  = threadIdx.x;
  __shared__ float xs[10][66];
  const float* xp = X + ((size_t)(b*C_ + c)) * NPIX;
  for (int i = t; i < 660; i += 256){
    int r = i / 66, col = i - r*66;
    int h = h0 - 1 + r, w = col - 1;
    float v = 0.f;
    if (h >= 0 && h < 64 && w >= 0 && w < 64) v = xp[h*64 + w];
    xs[r][col] = v;
  }
  __syncthreads();
  float wgt[9];
#pragma unroll
  for (int j = 0; j < 9; ++j) wgt[j] = W[c*9 + j];
  const float scale = G[c] * rsqrtf(Vr[c] + 1e-5f);
  const float mu = Mn[c], bb = Bb[c];
  short* op = O + ((size_t)(b*C_ + c)) * NPIX;
  for (int i = t; i < 512; i += 256){
    int r = i >> 6, w = i & 63;
    float s = 0.f;
#pragma unroll
    for (int dh = 0; dh < 3; ++dh)
#pragma unroll
      for (int dw = 0; dw < 3; ++dw)
        s += xs[r+dh][w+dw] * wgt[dh*3+dw];
    float y = (s - mu) * scale + bb;
    op[(h0 + r)*64 + w] = f2b(silu_f(y));
  }
}

// ---------- (b,c,s) -> (b,s,c) bf16 transpose ----------
__global__ void transpose_k(const short* __restrict__ I, short* __restrict__ O){
  const int s0 = blockIdx.x*32, c0 = blockIdx.y*32, b = blockIdx.z;
  const int tx = threadIdx.x & 31, ty = threadIdx.x >> 5;
  __shared__ short tile[32][33];
#pragma unroll
  for (int j = 0; j < 4; ++j)
    tile[ty + 8*j][tx] = I[((size_t)(b*C_ + c0 + ty + 8*j))*NPIX + s0 + tx];
  __syncthreads();
#pragma unroll
  for (int j = 0; j < 4; ++j)
    O[((size_t)(b*NPIX + s0 + ty + 8*j))*C_ + c0 + tx] = tile[tx][ty + 8*j];
}

// ---------- MFMA bf16 GEMM, X-as-A orientation ----------
// D[pixel][chan] = sum_k X[pixel][k] * Wt[chan][k].  Tile: 128 pix x 256 chan,
// BK=64.  EPI: 0 = P=acc (+stats); 1 = bf16 Obf = acc+bias;
// 2 = P += acc+bias (+stats); 3 = bf16 Obf = silu(acc+bias);
// 4 = f32 NCHW Of32 = BN(acc) via LDS restage; 5 = P += acc+bias at invpi pixel (+stats)
template<int EPI, int K>
__global__ __launch_bounds__(256, 2)
void gemm_k(const short* __restrict__ W, const short* __restrict__ X,
            const int M,
            const float* __restrict__ bias,
            float* __restrict__ P,
            short* __restrict__ Obf,
            float* __restrict__ Of32,
            const float* __restrict__ bng, const float* __restrict__ bnb,
            const float* __restrict__ bnm, const float* __restrict__ bnv,
            float* __restrict__ st)
{
  constexpr int S = K / 64;
  const int nt = blockIdx.x;          // pixel tile (128)
  const int ct = blockIdx.y;          // chan tile (256)
  const int b  = blockIdx.z;
  const int tid = threadIdx.x;
  const int ln = tid & 63, wv = tid >> 6;
  const int wy = wv >> 1;             // pixel half (64)
  const int wx = wv & 1;              // chan half (128)
  const int lr = ln & 15, lq = ln >> 4;
  const int rl = ln >> 3, sp = ln & 7;
  const int sw = sp ^ rl;             // staged global k-seg (XOR swizzle)

  __shared__ __align__(16) char smem[49152 + 64];
  short* As = (short*)smem;           // X tile: 128 rows x 64 (16 KB)
  short* Bs = (short*)(smem + 16384); // W tile: 256 rows x 64 (32 KB)
  float* CT = (float*)smem;           // EPI4 restage reuse
  float* r1 = (float*)(smem + 49152);
  float* r2 = r1 + 4;

  const short* Xp = X + ((size_t)b*NPIX + (size_t)nt*128) * K;
  const short* Wp = W + (size_t)ct*256*K;

  const short* gx[4]; short* lx[4];
  const short* gw[8]; short* lw[8];
#pragma unroll
  for (int j = 0; j < 4; ++j){
    const int row = 32*wv + 8*j + rl;
    gx[j] = Xp + (size_t)row*K + sw*8;
    lx[j] = As + (4*wv + j)*512;
  }
#pragma unroll
  for (int j = 0; j < 8; ++j){
    const int row = 64*wv + 8*j + rl;
    gw[j] = Wp + (size_t)row*K + sw*8;
    lw[j] = Bs + (8*wv + j)*512;
  }

  f32x4 acc[4][8];
#pragma unroll
  for (int r = 0; r < 4; ++r)
#pragma unroll
    for (int c = 0; c < 8; ++c) acc[r][c] = (f32x4){0.f,0.f,0.f,0.f};

  for (int stp = 0; stp < S; ++stp){
    if (stp) __syncthreads();
#pragma unroll
    for (int j = 0; j < 4; ++j) gld16(gx[j] + stp*64, lx[j]);
#pragma unroll
    for (int j = 0; j < 8; ++j) gld16(gw[j] + stp*64, lw[j]);
    __syncthreads();
#pragma unroll
    for (int kk = 0; kk < 2; ++kk){
      const int seg = ((kk*4 + lq) ^ (lr & 7)) * 16;   // byte offset in 128B row
      short8 ax[4], bw[8];
#pragma unroll
      for (int r = 0; r < 4; ++r)
        ax[r] = *(const short8*)((const char*)As + (wy*64 + r*16 + lr)*128 + seg);
#pragma unroll
      for (int c = 0; c < 8; ++c)
        bw[c] = *(const short8*)((const char*)Bs + (wx*128 + c*16 + lr)*128 + seg);
#pragma unroll
      for (int r = 0; r < 4; ++r)
#pragma unroll
        for (int c = 0; c < 8; ++c)
          acc[r][c] = __builtin_amdgcn_mfma_f32_16x16x32_bf16(ax[r], bw[c], acc[r][c], 0, 0, 0);
    }
  }

  // ---------- epilogue ----------
  if constexpr (EPI != 4){
    float bcol[8];
#pragma unroll
    for (int c = 0; c < 8; ++c)
      bcol[c] = (EPI == 1 || EPI == 2 || EPI == 3 || EPI == 5)
                ? bias[ct*256 + wx*128 + c*16 + lr] : 0.f;
    float sm = 0.f, ss = 0.f;
#pragma unroll
    for (int r = 0; r < 4; ++r){
      size_t rowbase[4];
#pragma unroll
      for (int j = 0; j < 4; ++j){
        int pix = nt*128 + wy*64 + r*16 + lq*4 + j;
        if constexpr (EPI == 5) pix = pi2pix(pix);
        rowbase[j] = (size_t)b*NPIX + pix;
      }
#pragma unroll
      for (int c = 0; c < 8; ++c){
        const int chan = ct*256 + wx*128 + c*16 + lr;
        f32x4 v = acc[r][c];
#pragma unroll
        for (int j = 0; j < 4; ++j){
          float val = v[j] + bcol[c];
          if constexpr (EPI == 0){
            P[rowbase[j]*256 + chan] = val;
            sm += val; ss += val*val;
          } else if constexpr (EPI == 2 || EPI == 5){
            float* pp = &P[rowbase[j]*256 + chan];
            float nv = *pp + val;
            *pp = nv;
            sm += nv; ss += nv*nv;
          } else if constexpr (EPI == 1){
            Obf[rowbase[j]*(size_t)M + chan] = f2b(val);
          } else {  // EPI == 3
            Obf[rowbase[j]*(size_t)M + chan] = f2b(silu_f(val));
          }
        }
      }
    }
    if constexpr (EPI == 0 || EPI == 2 || EPI == 5){
#pragma unroll
      for (int o = 32; o > 0; o >>= 1){ sm += __shfl_down(sm, o); ss += __shfl_down(ss, o); }
      if (ln == 0){ r1[wv] = sm; r2[wv] = ss; }
      __syncthreads();
      if (tid == 0){
        atomicAdd(&st[b*2+0], r1[0]+r1[1]+r1[2]+r1[3]);
        atomicAdd(&st[b*2+1], r2[0]+r2[1]+r2[2]+r2[3]);
      }
    }
  } else {
    // EPI 4: BN -> f32 NCHW out, restaged through LDS (4 chan-quarter passes)
#pragma unroll
    for (int p = 0; p < 4; ++p){
      __syncthreads();
      if (wx == (p >> 1)){
        const int cbase = (p & 1)*4;
#pragma unroll
        for (int r = 0; r < 4; ++r){
          const int pl = wy*64 + r*16 + lq*4;
#pragma unroll
          for (int cc = 0; cc < 4; ++cc){
            const int c = cbase + cc;
            const int chl = c*16 + lr - (p & 1)*64;   // 0..63
            *(f32x4*)&CT[chl*132 + pl] = acc[r][c];
          }
        }
      }
      __syncthreads();
      for (int idx = tid; idx < 64*32; idx += 256){
        const int chl = idx >> 5, sg = idx & 31;
        const int chan = ct*256 + p*64 + chl;
        f32x4 v = *(const f32x4*)&CT[chl*132 + sg*4];
        const float sc = bng[chan] * rsqrtf(bnv[chan] + 1e-5f);
        const float mu = bnm[chan], bb = bnb[chan];
        f32x4 o;
        o.x = (v.x - mu)*sc + bb; o.y = (v.y - mu)*sc + bb;
        o.z = (v.z - mu)*sc + bb; o.w = (v.w - mu)*sc + bb;
        *(f32x4*)&Of32[((size_t)(b*C_ + chan))*NPIX + (size_t)nt*128 + sg*4] = o;
      }
    }
  }
}

// ---------- GN apply (stats pre-computed by GEMM epilogues) ----------
template<bool PERM>
__global__ void gn_apply_k(const float* __restrict__ P, const float* __restrict__ st,
                           const float* __restrict__ G, const float* __restrict__ Bb,
                           short* __restrict__ U){
  const int b = blockIdx.y;
  const float mean = st[b*2]   * (1.f/NE_PB);
  const float var  = st[b*2+1] * (1.f/NE_PB) - mean*mean;
  const float inv  = rsqrtf(var + 1e-5f);
  const int t = threadIdx.x;
  const int c0 = (t*4) & 255;
  const f32x4 g4 = *(const f32x4*)&G[c0];
  const f32x4 b4 = *(const f32x4*)&Bb[c0];
  const size_t base = (size_t)b*NE_PB + (size_t)blockIdx.x*16384 + t*4;
#pragma unroll
  for (int i = 0; i < 16; ++i){
    const size_t e = (size_t)blockIdx.x*16384 + t*4 + (size_t)i*1024;
    f32x4 v = *(const f32x4*)&P[base + (size_t)i*1024];
    short4v o;
    o.x = f2b((v.x - mean)*inv*g4.x + b4.x);
    o.y = f2b((v.y - mean)*inv*g4.y + b4.y);
    o.z = f2b((v.z - mean)*inv*g4.z + b4.z);
    o.w = f2b((v.w - mean)*inv*g4.w + b4.w);
    if constexpr (PERM){
      const int pix = (int)(e >> 8);
      *(short4v*)&U[((size_t)b*NPIX + pix2pi(pix))*256 + c0] = o;
    } else {
      *(short4v*)&U[base + (size_t)i*1024] = o;
    }
  }
}

// ---------- q = Wq . u + qb  (one wave per pixel row; rows in pi-order) ----------
__global__ void q_k(const short* __restrict__ U, const float* __restrict__ Wq,
                    const float* __restrict__ Qb, float* __restrict__ Q){
  const int lane = threadIdx.x & 63;
  const int pix = (blockIdx.x*256 + threadIdx.x) >> 6;  // global pi-row 0..65535
  short4v u4 = *(const short4v*)&U[(size_t)pix*256 + lane*4];
  f32x4  w4 = *(const f32x4*)&Wq[lane*4];
  float s = b2f(u4.x)*w4.x + b2f(u4.y)*w4.y + b2f(u4.z)*w4.z + b2f(u4.w)*w4.w;
#pragma unroll
  for (int o = 32; o > 0; o >>= 1) s += __shfl_down(s, o);
  if (lane == 0) Q[pix] = s + Qb[0];
}

// ---------- softmax over 1024 contiguous pi-pixels; also zeroes ctx accum ----------
__global__ void softmax_k(const float* __restrict__ Q, float* __restrict__ S,
                          float* __restrict__ CT){
  const int bp = blockIdx.x;
  const int t = threadIdx.x;
  CT[bp*256 + t] = 0.f;
  float vals[4];
  float mx = -1e30f;
#pragma unroll
  for (int j = 0; j < 4; ++j){
    vals[j] = Q[bp*1024 + t + j*256];
    mx = fmaxf(mx, vals[j]);
  }
  __shared__ float red[4];
  const int lane = t & 63, wv = t >> 6;
#pragma unroll
  for (int o = 32; o > 0; o >>= 1) mx = fmaxf(mx, __shfl_down(mx, o));
  if (lane == 0) red[wv] = mx;
  __syncthreads();
  mx = fmaxf(fmaxf(red[0], red[1]), fmaxf(red[2], red[3]));
  __syncthreads();
  float sum = 0.f;
#pragma unroll
  for (int j = 0; j < 4; ++j){ vals[j] = expf(vals[j] - mx); sum += vals[j]; }
#pragma unroll
  for (int o = 32; o > 0; o >>= 1) sum += __shfl_down(sum, o);
  if (lane == 0) red[wv] = sum;
  __syncthreads();
  sum = red[0] + red[1] + red[2] + red[3];
  const float r = 1.f / sum;
#pragma unroll
  for (int j = 0; j < 4; ++j) S[bp*1024 + t + j*256] = vals[j]*r;
}

// ---------- ctx[bp][c] = sum_n k[bp*1024+n][c] * s[bp][n]  (coalesced, atomics) ----------
__global__ void ctx_k(const short* __restrict__ KV, const float* __restrict__ S,
                      float* __restrict__ CT){
  const int bp = blockIdx.x, ch = blockIdx.y;
  const int ln = threadIdx.x & 63, wv = threadIdx.x >> 6;
  const int j0 = ch*256 + wv*64;
  f32x4 acc = (f32x4){0.f,0.f,0.f,0.f};
  for (int jj = 0; jj < 64; jj += 4){
    f32x4 s4 = *(const f32x4*)&S[bp*1024 + j0 + jj];
#pragma unroll
    for (int u = 0; u < 4; ++u){
      short4v kv = *(const short4v*)&KV[((size_t)bp*1024 + j0 + jj + u)*512 + ln*4];
      const float s = s4[u];
      acc.x += b2f(kv.x)*s; acc.y += b2f(kv.y)*s;
      acc.z += b2f(kv.z)*s; acc.w += b2f(kv.w)*s;
    }
  }
  atomicAdd(&CT[bp*256 + ln*4 + 0], acc.x);
  atomicAdd(&CT[bp*256 + ln*4 + 1], acc.y);
  atomicAdd(&CT[bp*256 + ln*4 + 2], acc.z);
  atomicAdd(&CT[bp*256 + ln*4 + 3], acc.w);
}

// ---------- attn input: relu(v) * ctx[parity]  (all pi-ordered) ----------
__global__ void attn_in_k(const short* __restrict__ KV, const float* __restrict__ CT,
                          short* __restrict__ O){
  const size_t vid = (size_t)blockIdx.x*256 + threadIdx.x;
  const int c4 = (int)(vid & 63);
  const size_t r = vid >> 6;                // global pi row = b*4096 + p*1024 + idx
  const int bp = (int)(r >> 10);
  short4v v4 = *(const short4v*)&KV[r*512 + 256 + c4*4];
  f32x4  cx = *(const f32x4*)&CT[bp*256 + c4*4];
  short4v o;
  o.x = f2b(fmaxf(b2f(v4.x), 0.f)*cx.x);
  o.y = f2b(fmaxf(b2f(v4.y), 0.f)*cx.y);
  o.z = f2b(fmaxf(b2f(v4.z), 0.f)*cx.z);
  o.w = f2b(fmaxf(b2f(v4.w), 0.f)*cx.w);
  *(short4v*)&O[r*256 + c4*4] = o;
}

extern "C" void kernel_launch(void* const* d_in, const int* in_sizes, int n_in,
                              void* d_out, int out_size, void* d_ws, size_t ws_size,
                              hipStream_t stream){
  const float* x      = (const float*)d_in[0];
  const float* dw_w   = (const float*)d_in[1];
  const float* dw_g   = (const float*)d_in[2];
  const float* dw_b   = (const float*)d_in[3];
  const float* dw_m   = (const float*)d_in[4];
  const float* dw_v   = (const float*)d_in[5];
  const float* pw_w   = (const float*)d_in[6];
  const float* gn1_g  = (const float*)d_in[7];
  const float* gn1_b  = (const float*)d_in[8];
  const float* qkv_w  = (const float*)d_in[9];
  const float* qkv_b  = (const float*)d_in[10];
  const float* out_w  = (const float*)d_in[11];
  const float* out_b  = (const float*)d_in[12];
  const float* gn2_g  = (const float*)d_in[13];
  const float* gn2_b  = (const float*)d_in[14];
  const float* ffn1_w = (const float*)d_in[15];
  const float* ffn1_b = (const float*)d_in[16];
  const float* ffn2_w = (const float*)d_in[17];
  const float* ffn2_b = (const float*)d_in[18];
  const float* gnf_g  = (const float*)d_in[19];
  const float* gnf_b  = (const float*)d_in[20];
  const float* proj_w = (const float*)d_in[21];
  const float* pbn_g  = (const float*)d_in[22];
  const float* pbn_b  = (const float*)d_in[23];
  const float* pbn_m  = (const float*)d_in[24];
  const float* pbn_v  = (const float*)d_in[25];
  float* out = (float*)d_out;

  uint8_t* w8 = (uint8_t*)d_ws;
  float* P     = (float*)(w8);                 // fp32 residual, 64 MiB
  short* bufA  = (short*)(w8 + 67108864);      // bf16 (B,4096,256), 32 MiB
  short* bufB  = (short*)(w8 + 100663296);     // bf16 (B,4096,512), 64 MiB
  short* w_pw  = (short*)(w8 + 167772160);
  short* w_qkv = (short*)(w8 + 167903232);
  short* w_out = (short*)(w8 + 168428544);
  short* w_f1  = (short*)(w8 + 168690688);
  short* w_f2  = (short*)(w8 + 169214976);
  short* w_pj  = (short*)(w8 + 169739264);
  float* qbuf  = (float*)(w8 + 169870336);     // (B*4096)
  float* scor  = (float*)(w8 + 170132480);     // (64,1024)
  float* ctxs  = (float*)(w8 + 170394624);     // (64,256)
  float* stats = (float*)(w8 + 170918912);     // 5 sites x 16 x 2

  // weight casts + stats zeroing
  cvt_k<<<256, 256, 0, stream>>>(pw_w,   w_pw,  65536);
  cvt_k<<<1027, 256, 0, stream>>>(qkv_w, w_qkv, 262656);
  cvt_k<<<512, 256, 0, stream>>>(out_w,  w_out, 131072);
  cvt_k<<<1024, 256, 0, stream>>>(ffn1_w, w_f1, 262144);
  cvt_k<<<1024, 256, 0, stream>>>(ffn2_w, w_f2, 262144);
  cvt_k<<<256, 256, 0, stream>>>(proj_w, w_pj,  65536);
  zero_k<<<1, 256, 0, stream>>>(stats, 160);

  dwconv_k<<<dim3(8,256,16), 256, 0, stream>>>(x, dw_w, dw_g, dw_b, dw_m, dw_v, bufB);
  transpose_k<<<dim3(128,8,16), 256, 0, stream>>>(bufB, bufA);

  // pw conv -> P (stats site 0 = gn1 layer 0)
  gemm_k<0,256><<<dim3(32,1,16), 256, 0, stream>>>(w_pw, bufA, 256, nullptr, P,
      nullptr, nullptr, nullptr, nullptr, nullptr, nullptr, stats + 0);

  for (int i = 0; i < 2; ++i){
    float* st1 = stats + (i == 0 ? 0 : 2*32);            // gn1 site
    gn_apply_k<true><<<dim3(64,16), 256, 0, stream>>>(P, st1, gn1_g + i*256, gn1_b + i*256, bufA);
    q_k<<<16384, 256, 0, stream>>>(bufA, qkv_w + i*513*256, qkv_b + i*513, qbuf);
    gemm_k<1,256><<<dim3(32,2,16), 256, 0, stream>>>(w_qkv + (i*513+1)*256, bufA, 512,
        qkv_b + i*513 + 1, nullptr, bufB, nullptr, nullptr, nullptr, nullptr, nullptr, nullptr);
    softmax_k<<<64, 256, 0, stream>>>(qbuf, scor, ctxs);
    ctx_k<<<dim3(64,4), 256, 0, stream>>>(bufB, scor, ctxs);
    attn_in_k<<<16384, 256, 0, stream>>>(bufB, ctxs, bufA);
    // out proj: P += (unpermute), stats -> gn2 site
    gemm_k<5,256><<<dim3(32,1,16), 256, 0, stream>>>(w_out + i*65536, bufA, 256,
        out_b + i*256, P, nullptr, nullptr, nullptr, nullptr, nullptr, nullptr,
        stats + (i == 0 ? 1 : 3)*32);
    float* st2 = stats + (i == 0 ? 1 : 3)*32;
    gn_apply_k<false><<<dim3(64,16), 256, 0, stream>>>(P, st2, gn2_g + i*256, gn2_b + i*256, bufA);
    gemm_k<3,256><<<dim3(32,2,16), 256, 0, stream>>>(w_f1 + i*131072, bufA, 512,
        ffn1_b + i*512, nullptr, bufB, nullptr, nullptr, nullptr, nullptr, nullptr, nullptr);
    // ffn2: P += , stats -> next gn1 site (i=0) or gnf site (i=1)
    gemm_k<2,512><<<dim3(32,1,16), 256, 0, stream>>>(w_f2 + i*131072, bufB, 256,
        ffn2_b + i*256, P, nullptr, nullptr, nullptr, nullptr, nullptr, nullptr,
        stats + (i == 0 ? 2 : 4)*32);
  }

  gn_apply_k<false><<<dim3(64,16), 256, 0, stream>>>(P, stats + 4*32, gnf_g, gnf_b, bufA);
  gemm_k<4,256><<<dim3(32,1,16), 256, 0, stream>>>(w_pj, bufA, 256, nullptr,
      nullptr, nullptr, out, pbn_g, pbn_b, pbn_m, pbn_v, nullptr);

  (void)in_sizes; (void)n_in; (void)out_size; (void)ws_size;
}

// Round 4
// 767.510 us; speedup vs baseline: 1.2676x; 1.1221x over previous
//
#include <hip/hip_runtime.h>
#include <hip/hip_bf16.h>
#include <stdint.h>

// MobileViTBlockV2: B=16, C=256, H=W=64, D=256, F=512, L=2, patch 2x2.
// R4: W-as-A MFMA GEMM (chan on reg axis), 128x128 tile, BK=64 XOR-swizzled
// global_load_lds staging (0 conflicts, measured R3), LDS-restaged epilogue
// with 512B/256B contiguous runs per pixel, fused GN stats, parity-permuted
// attention path.

#define B_    16
#define C_    256
#define D_    256
#define NPIX  4096
#define NE_PB 1048576   // D_*NPIX elements per batch for GN

typedef __attribute__((ext_vector_type(8))) short  short8;
typedef __attribute__((ext_vector_type(4))) short  short4v;
typedef __attribute__((ext_vector_type(4))) float  f32x4;

__device__ __forceinline__ float b2f(short s){
  return __uint_as_float(((unsigned)(unsigned short)s) << 16);
}
__device__ __forceinline__ short f2b(float f){
  unsigned u = __float_as_uint(f);
  return (short)((u + 0x7fffu + ((u >> 16) & 1u)) >> 16);  // RNE
}
__device__ __forceinline__ float silu_f(float x){ return x / (1.f + expf(-x)); }

__device__ __forceinline__ void gld16(const short* g, short* l){
  __builtin_amdgcn_global_load_lds(
      (const __attribute__((address_space(1))) void*)g,
      (__attribute__((address_space(3))) void*)l, 16, 0, 0);
}

// pixel -> parity-permuted index: pi = parity*1024 + (h/2)*32 + (w/2)
__device__ __forceinline__ int pix2pi(int pix){
  int h = pix >> 6, w = pix & 63;
  return ((h & 1)*2 + (w & 1))*1024 + (h >> 1)*32 + (w >> 1);
}
__device__ __forceinline__ int pi2pix(int n){
  int p = n >> 10, idx = n & 1023;
  int h = ((idx >> 5) << 1) | (p >> 1);
  int w = ((idx & 31) << 1) | (p & 1);
  return h*64 + w;
}

// ---------- small prep kernels ----------
__global__ void cvt_k(const float* __restrict__ s, short* __restrict__ d, int n){
  int i = blockIdx.x*256 + threadIdx.x;
  if (i < n) d[i] = f2b(s[i]);
}
__global__ void zero_k(float* __restrict__ p, int n){
  int i = blockIdx.x*256 + threadIdx.x;
  if (i < n) p[i] = 0.f;
}

// ---------- dwconv3x3 + BN + SiLU (channel-major in, channel-major bf16 out) ----------
__global__ void dwconv_k(const float* __restrict__ X, const float* __restrict__ W,
                         const float* __restrict__ G, const float* __restrict__ Bb,
                         const float* __restrict__ Mn, const float* __restrict__ Vr,
                         short* __restrict__ O){
  const int h0 = blockIdx.x * 8;
  const int c  = blockIdx.y;
  const int b  = blockIdx.z;
  const int t  = threadIdx.x;
  __shared__ float xs[10][66];
  const float* xp = X + ((size_t)(b*C_ + c)) * NPIX;
  for (int i = t; i < 660; i += 256){
    int r = i / 66, col = i - r*66;
    int h = h0 - 1 + r, w = col - 1;
    float v = 0.f;
    if (h >= 0 && h < 64 && w >= 0 && w < 64) v = xp[h*64 + w];
    xs[r][col] = v;
  }
  __syncthreads();
  float wgt[9];
#pragma unroll
  for (int j = 0; j < 9; ++j) wgt[j] = W[c*9 + j];
  const float scale = G[c] * rsqrtf(Vr[c] + 1e-5f);
  const float mu = Mn[c], bb = Bb[c];
  short* op = O + ((size_t)(b*C_ + c)) * NPIX;
  for (int i = t; i < 512; i += 256){
    int r = i >> 6, w = i & 63;
    float s = 0.f;
#pragma unroll
    for (int dh = 0; dh < 3; ++dh)
#pragma unroll
      for (int dw = 0; dw < 3; ++dw)
        s += xs[r+dh][w+dw] * wgt[dh*3+dw];
    float y = (s - mu) * scale + bb;
    op[(h0 + r)*64 + w] = f2b(silu_f(y));
  }
}

// ---------- (b,c,s) -> (b,s,c) bf16 transpose ----------
__global__ void transpose_k(const short* __restrict__ I, short* __restrict__ O){
  const int s0 = blockIdx.x*32, c0 = blockIdx.y*32, b = blockIdx.z;
  const int tx = threadIdx.x & 31, ty = threadIdx.x >> 5;
  __shared__ short tile[32][33];
#pragma unroll
  for (int j = 0; j < 4; ++j)
    tile[ty + 8*j][tx] = I[((size_t)(b*C_ + c0 + ty + 8*j))*NPIX + s0 + tx];
  __syncthreads();
#pragma unroll
  for (int j = 0; j < 4; ++j)
    O[((size_t)(b*NPIX + s0 + ty + 8*j))*C_ + c0 + tx] = tile[tx][ty + 8*j];
}

// ---------- MFMA bf16 GEMM: D[pix][chan] = sum_k X[pix][k]*Wt[chan][k] ----------
// Tile 128 pix x 128 chan, BK=64. W is the MFMA A operand (chan on reg axis).
// EPI: 0 = P=acc (+stats); 1 = bf16 Obf = acc+bias; 2 = P += acc+bias (+stats);
// 3 = bf16 Obf = silu(acc+bias); 4 = f32 NCHW Of32 = BN(acc);
// 5 = P += acc+bias at pi2pix(row) (+stats)
template<int EPI, int K>
__global__ __launch_bounds__(256, 3)
void gemm_k(const short* __restrict__ Wt, const short* __restrict__ X,
            const int M,
            const float* __restrict__ bias,
            float* __restrict__ P,
            short* __restrict__ Obf,
            float* __restrict__ Of32,
            const float* __restrict__ bng, const float* __restrict__ bnb,
            const float* __restrict__ bnm, const float* __restrict__ bnv,
            float* __restrict__ st)
{
  constexpr int S = K / 64;
  const int nt = blockIdx.x;          // pixel tile (128)
  const int ct = blockIdx.y;          // chan tile (128)
  const int b  = blockIdx.z;
  const int tid = threadIdx.x;
  const int ln = tid & 63, wv = tid >> 6;
  const int wx = wv & 1;              // chan half (64)
  const int wy = wv >> 1;             // pixel half (64)
  const int lr = ln & 15, lq = ln >> 4;
  const int rl = ln >> 3, sp = ln & 7;
  const int sw = sp ^ rl;             // staged k-seg (XOR swizzle)

  __shared__ __align__(16) char smem[33824];
  short* As = (short*)smem;            // W tile: 128 chan rows x 64 k (16 KB)
  short* Xs = (short*)(smem + 16384);  // X tile: 128 pix rows x 64 k (16 KB)
  float* CT = (float*)smem;            // epilogue restage (64x132 f32)
  float* red = (float*)(smem + 33792); // 8 floats

  const short* Wp = Wt + (size_t)(ct*128)*K;
  const short* Xp = X + ((size_t)b*NPIX + (size_t)nt*128) * K;

  const short* gw[4]; const short* gx[4]; short* lw[4]; short* lx[4];
#pragma unroll
  for (int j = 0; j < 4; ++j){
    const int row = 32*wv + 8*j + rl;
    gw[j] = Wp + (size_t)row*K + sw*8;
    gx[j] = Xp + (size_t)row*K + sw*8;
    lw[j] = As + (4*wv + j)*512;
    lx[j] = Xs + (4*wv + j)*512;
  }

  f32x4 acc[4][4];
#pragma unroll
  for (int r = 0; r < 4; ++r)
#pragma unroll
    for (int c = 0; c < 4; ++c) acc[r][c] = (f32x4){0.f,0.f,0.f,0.f};

  for (int stp = 0; stp < S; ++stp){
    if (stp) __syncthreads();
#pragma unroll
    for (int j = 0; j < 4; ++j) gld16(gw[j] + stp*64, lw[j]);
#pragma unroll
    for (int j = 0; j < 4; ++j) gld16(gx[j] + stp*64, lx[j]);
    __syncthreads();
#pragma unroll
    for (int kk = 0; kk < 2; ++kk){
      const int seg = ((kk*4 + lq) ^ (lr & 7)) * 16;   // byte offset in 128B row
      short8 aw[4], bx[4];
#pragma unroll
      for (int r = 0; r < 4; ++r)
        aw[r] = *(const short8*)((const char*)As + (wx*64 + r*16 + lr)*128 + seg);
#pragma unroll
      for (int c = 0; c < 4; ++c)
        bx[c] = *(const short8*)((const char*)Xs + (wy*64 + c*16 + lr)*128 + seg);
#pragma unroll
      for (int r = 0; r < 4; ++r)
#pragma unroll
        for (int c = 0; c < 4; ++c)
          acc[r][c] = __builtin_amdgcn_mfma_f32_16x16x32_bf16(aw[r], bx[c], acc[r][c], 0, 0, 0);
    }
  }
  // acc[r][c]: chan = ct*128 + wx*64 + r*16 + lq*4 + reg ; pix = nt*128 + wy*64 + c*16 + lr

  const int ccS = (tid & 31) * 4;      // store-phase chan offset within 128
  f32x4 bv = (f32x4){0.f,0.f,0.f,0.f};
  if constexpr (EPI == 1 || EPI == 2 || EPI == 3 || EPI == 5)
    bv = *(const f32x4*)&bias[ct*128 + ccS];

  float sm = 0.f, ss = 0.f;

  if constexpr (EPI != 4){
    // 2 passes over pixel halves; CT[pixL 0..63][chan 0..127], stride 132
#pragma unroll
    for (int p = 0; p < 2; ++p){
      __syncthreads();
      if (wy == p){
#pragma unroll
        for (int r = 0; r < 4; ++r)
#pragma unroll
          for (int c = 0; c < 4; ++c)
            *(f32x4*)&CT[(c*16 + lr)*132 + wx*64 + r*16 + lq*4] = acc[r][c];
      }
      __syncthreads();
#pragma unroll
      for (int it = 0; it < 8; ++it){
        const int idx = it*256 + tid;
        const int pixL = idx >> 5;
        f32x4 v = *(const f32x4*)&CT[pixL*132 + ccS];
        v.x += bv.x; v.y += bv.y; v.z += bv.z; v.w += bv.w;
        int pixg = nt*128 + p*64 + pixL;
        if constexpr (EPI == 5) pixg = pi2pix(pixg);
        const size_t rowb = (size_t)b*NPIX + pixg;
        if constexpr (EPI == 0){
          *(f32x4*)&P[rowb*256 + ct*128 + ccS] = v;
          sm += v.x + v.y + v.z + v.w;
          ss += v.x*v.x + v.y*v.y + v.z*v.z + v.w*v.w;
        } else if constexpr (EPI == 2 || EPI == 5){
          float* pp = &P[rowb*256 + ct*128 + ccS];
          f32x4 o = *(const f32x4*)pp;
          o.x += v.x; o.y += v.y; o.z += v.z; o.w += v.w;
          *(f32x4*)pp = o;
          sm += o.x + o.y + o.z + o.w;
          ss += o.x*o.x + o.y*o.y + o.z*o.z + o.w*o.w;
        } else if constexpr (EPI == 1){
          short4v o;
          o.x = f2b(v.x); o.y = f2b(v.y); o.z = f2b(v.z); o.w = f2b(v.w);
          *(short4v*)&Obf[rowb*(size_t)M + ct*128 + ccS] = o;
        } else {  // EPI == 3
          short4v o;
          o.x = f2b(silu_f(v.x)); o.y = f2b(silu_f(v.y));
          o.z = f2b(silu_f(v.z)); o.w = f2b(silu_f(v.w));
          *(short4v*)&Obf[rowb*(size_t)M + ct*128 + ccS] = o;
        }
      }
    }
    if constexpr (EPI == 0 || EPI == 2 || EPI == 5){
#pragma unroll
      for (int o = 32; o > 0; o >>= 1){ sm += __shfl_down(sm, o); ss += __shfl_down(ss, o); }
      if (ln == 0){ red[wv*2] = sm; red[wv*2+1] = ss; }
      __syncthreads();
      if (tid == 0){
        atomicAdd(&st[b*2+0], red[0]+red[2]+red[4]+red[6]);
        atomicAdd(&st[b*2+1], red[1]+red[3]+red[5]+red[7]);
      }
    }
  } else {
    // EPI 4: BN -> f32 NCHW; 2 passes over chan halves; CT[chanL 0..63][pix 0..127], stride 132
#pragma unroll
    for (int p = 0; p < 2; ++p){
      __syncthreads();
      if (wx == p){
#pragma unroll
        for (int r = 0; r < 4; ++r)
#pragma unroll
          for (int c = 0; c < 4; ++c){
            const int pixL = wy*64 + c*16 + lr;
#pragma unroll
            for (int j = 0; j < 4; ++j)
              CT[(r*16 + lq*4 + j)*132 + pixL] = acc[r][c][j];
          }
      }
      __syncthreads();
#pragma unroll
      for (int it = 0; it < 8; ++it){
        const int idx = it*256 + tid;
        const int chL = idx >> 5, pq = (idx & 31)*4;
        const int chan = ct*128 + p*64 + chL;
        f32x4 v = *(const f32x4*)&CT[chL*132 + pq];
        const float sc = bng[chan] * rsqrtf(bnv[chan] + 1e-5f);
        const float mu = bnm[chan], bb = bnb[chan];
        f32x4 o;
        o.x = (v.x - mu)*sc + bb; o.y = (v.y - mu)*sc + bb;
        o.z = (v.z - mu)*sc + bb; o.w = (v.w - mu)*sc + bb;
        *(f32x4*)&Of32[((size_t)(b*C_ + chan))*NPIX + (size_t)nt*128 + pq] = o;
      }
    }
  }
}

// ---------- GN apply (stats pre-computed by GEMM epilogues) ----------
template<bool PERM>
__global__ void gn_apply_k(const float* __restrict__ P, const float* __restrict__ st,
                           const float* __restrict__ G, const float* __restrict__ Bb,
                           short* __restrict__ U){
  const int b = blockIdx.y;
  const float mean = st[b*2]   * (1.f/NE_PB);
  const float var  = st[b*2+1] * (1.f/NE_PB) - mean*mean;
  const float inv  = rsqrtf(var + 1e-5f);
  const int t = threadIdx.x;
  const int c0 = (t*4) & 255;
  const f32x4 g4 = *(const f32x4*)&G[c0];
  const f32x4 b4 = *(const f32x4*)&Bb[c0];
  const size_t base = (size_t)b*NE_PB + (size_t)blockIdx.x*16384 + t*4;
#pragma unroll
  for (int i = 0; i < 16; ++i){
    const size_t e = (size_t)blockIdx.x*16384 + t*4 + (size_t)i*1024;
    f32x4 v = *(const f32x4*)&P[base + (size_t)i*1024];
    short4v o;
    o.x = f2b((v.x - mean)*inv*g4.x + b4.x);
    o.y = f2b((v.y - mean)*inv*g4.y + b4.y);
    o.z = f2b((v.z - mean)*inv*g4.z + b4.z);
    o.w = f2b((v.w - mean)*inv*g4.w + b4.w);
    if constexpr (PERM){
      const int pix = (int)(e >> 8);
      *(short4v*)&U[((size_t)b*NPIX + pix2pi(pix))*256 + c0] = o;
    } else {
      *(short4v*)&U[base + (size_t)i*1024] = o;
    }
  }
}

// ---------- q = Wq . u + qb  (one wave per pixel row; rows in pi-order) ----------
__global__ void q_k(const short* __restrict__ U, const float* __restrict__ Wq,
                    const float* __restrict__ Qb, float* __restrict__ Q){
  const int lane = threadIdx.x & 63;
  const int pix = (blockIdx.x*256 + threadIdx.x) >> 6;
  short4v u4 = *(const short4v*)&U[(size_t)pix*256 + lane*4];
  f32x4  w4 = *(const f32x4*)&Wq[lane*4];
  float s = b2f(u4.x)*w4.x + b2f(u4.y)*w4.y + b2f(u4.z)*w4.z + b2f(u4.w)*w4.w;
#pragma unroll
  for (int o = 32; o > 0; o >>= 1) s += __shfl_down(s, o);
  if (lane == 0) Q[pix] = s + Qb[0];
}

// ---------- softmax over 1024 contiguous pi-pixels; also zeroes ctx accum ----------
__global__ void softmax_k(const float* __restrict__ Q, float* __restrict__ S,
                          float* __restrict__ CT){
  const int bp = blockIdx.x;
  const int t = threadIdx.x;
  CT[bp*256 + t] = 0.f;
  float vals[4];
  float mx = -1e30f;
#pragma unroll
  for (int j = 0; j < 4; ++j){
    vals[j] = Q[bp*1024 + t + j*256];
    mx = fmaxf(mx, vals[j]);
  }
  __shared__ float red[4];
  const int lane = t & 63, wv = t >> 6;
#pragma unroll
  for (int o = 32; o > 0; o >>= 1) mx = fmaxf(mx, __shfl_down(mx, o));
  if (lane == 0) red[wv] = mx;
  __syncthreads();
  mx = fmaxf(fmaxf(red[0], red[1]), fmaxf(red[2], red[3]));
  __syncthreads();
  float sum = 0.f;
#pragma unroll
  for (int j = 0; j < 4; ++j){ vals[j] = expf(vals[j] - mx); sum += vals[j]; }
#pragma unroll
  for (int o = 32; o > 0; o >>= 1) sum += __shfl_down(sum, o);
  if (lane == 0) red[wv] = sum;
  __syncthreads();
  sum = red[0] + red[1] + red[2] + red[3];
  const float r = 1.f / sum;
#pragma unroll
  for (int j = 0; j < 4; ++j) S[bp*1024 + t + j*256] = vals[j]*r;
}

// ---------- ctx[bp][c] = sum_n k[bp*1024+n][c] * s[bp][n]  (coalesced, atomics) ----------
__global__ void ctx_k(const short* __restrict__ KV, const float* __restrict__ S,
                      float* __restrict__ CT){
  const int bp = blockIdx.x, ch = blockIdx.y;
  const int ln = threadIdx.x & 63, wv = threadIdx.x >> 6;
  const int j0 = ch*256 + wv*64;
  f32x4 acc = (f32x4){0.f,0.f,0.f,0.f};
  for (int jj = 0; jj < 64; jj += 4){
    f32x4 s4 = *(const f32x4*)&S[bp*1024 + j0 + jj];
#pragma unroll
    for (int u = 0; u < 4; ++u){
      short4v kv = *(const short4v*)&KV[((size_t)bp*1024 + j0 + jj + u)*512 + ln*4];
      const float s = s4[u];
      acc.x += b2f(kv.x)*s; acc.y += b2f(kv.y)*s;
      acc.z += b2f(kv.z)*s; acc.w += b2f(kv.w)*s;
    }
  }
  atomicAdd(&CT[bp*256 + ln*4 + 0], acc.x);
  atomicAdd(&CT[bp*256 + ln*4 + 1], acc.y);
  atomicAdd(&CT[bp*256 + ln*4 + 2], acc.z);
  atomicAdd(&CT[bp*256 + ln*4 + 3], acc.w);
}

// ---------- attn input: relu(v) * ctx[parity]  (all pi-ordered) ----------
__global__ void attn_in_k(const short* __restrict__ KV, const float* __restrict__ CT,
                          short* __restrict__ O){
  const size_t vid = (size_t)blockIdx.x*256 + threadIdx.x;
  const int c4 = (int)(vid & 63);
  const size_t r = vid >> 6;
  const int bp = (int)(r >> 10);
  short4v v4 = *(const short4v*)&KV[r*512 + 256 + c4*4];
  f32x4  cx = *(const f32x4*)&CT[bp*256 + c4*4];
  short4v o;
  o.x = f2b(fmaxf(b2f(v4.x), 0.f)*cx.x);
  o.y = f2b(fmaxf(b2f(v4.y), 0.f)*cx.y);
  o.z = f2b(fmaxf(b2f(v4.z), 0.f)*cx.z);
  o.w = f2b(fmaxf(b2f(v4.w), 0.f)*cx.w);
  *(short4v*)&O[r*256 + c4*4] = o;
}

extern "C" void kernel_launch(void* const* d_in, const int* in_sizes, int n_in,
                              void* d_out, int out_size, void* d_ws, size_t ws_size,
                              hipStream_t stream){
  const float* x      = (const float*)d_in[0];
  const float* dw_w   = (const float*)d_in[1];
  const float* dw_g   = (const float*)d_in[2];
  const float* dw_b   = (const float*)d_in[3];
  const float* dw_m   = (const float*)d_in[4];
  const float* dw_v   = (const float*)d_in[5];
  const float* pw_w   = (const float*)d_in[6];
  const float* gn1_g  = (const float*)d_in[7];
  const float* gn1_b  = (const float*)d_in[8];
  const float* qkv_w  = (const float*)d_in[9];
  const float* qkv_b  = (const float*)d_in[10];
  const float* out_w  = (const float*)d_in[11];
  const float* out_b  = (const float*)d_in[12];
  const float* gn2_g  = (const float*)d_in[13];
  const float* gn2_b  = (const float*)d_in[14];
  const float* ffn1_w = (const float*)d_in[15];
  const float* ffn1_b = (const float*)d_in[16];
  const float* ffn2_w = (const float*)d_in[17];
  const float* ffn2_b = (const float*)d_in[18];
  const float* gnf_g  = (const float*)d_in[19];
  const float* gnf_b  = (const float*)d_in[20];
  const float* proj_w = (const float*)d_in[21];
  const float* pbn_g  = (const float*)d_in[22];
  const float* pbn_b  = (const float*)d_in[23];
  const float* pbn_m  = (const float*)d_in[24];
  const float* pbn_v  = (const float*)d_in[25];
  float* out = (float*)d_out;

  uint8_t* w8 = (uint8_t*)d_ws;
  float* P     = (float*)(w8);                 // fp32 residual, 64 MiB
  short* bufA  = (short*)(w8 + 67108864);      // bf16 (B,4096,256), 32 MiB
  short* bufB  = (short*)(w8 + 100663296);     // bf16 (B,4096,512), 64 MiB
  short* w_pw  = (short*)(w8 + 167772160);
  short* w_qkv = (short*)(w8 + 167903232);
  short* w_out = (short*)(w8 + 168428544);
  short* w_f1  = (short*)(w8 + 168690688);
  short* w_f2  = (short*)(w8 + 169214976);
  short* w_pj  = (short*)(w8 + 169739264);
  float* qbuf  = (float*)(w8 + 169870336);     // (B*4096)
  float* scor  = (float*)(w8 + 170132480);     // (64,1024)
  float* ctxs  = (float*)(w8 + 170394624);     // (64,256)
  float* stats = (float*)(w8 + 170918912);     // 5 sites x 16 x 2

  // weight casts + stats zeroing
  cvt_k<<<256, 256, 0, stream>>>(pw_w,   w_pw,  65536);
  cvt_k<<<1027, 256, 0, stream>>>(qkv_w, w_qkv, 262656);
  cvt_k<<<512, 256, 0, stream>>>(out_w,  w_out, 131072);
  cvt_k<<<1024, 256, 0, stream>>>(ffn1_w, w_f1, 262144);
  cvt_k<<<1024, 256, 0, stream>>>(ffn2_w, w_f2, 262144);
  cvt_k<<<256, 256, 0, stream>>>(proj_w, w_pj,  65536);
  zero_k<<<1, 256, 0, stream>>>(stats, 160);

  dwconv_k<<<dim3(8,256,16), 256, 0, stream>>>(x, dw_w, dw_g, dw_b, dw_m, dw_v, bufB);
  transpose_k<<<dim3(128,8,16), 256, 0, stream>>>(bufB, bufA);

  // pw conv -> P (stats site 0 = gn1 layer 0)
  gemm_k<0,256><<<dim3(32,2,16), 256, 0, stream>>>(w_pw, bufA, 256, nullptr, P,
      nullptr, nullptr, nullptr, nullptr, nullptr, nullptr, stats + 0);

  for (int i = 0; i < 2; ++i){
    float* st1 = stats + (i == 0 ? 0 : 2*32);            // gn1 site
    gn_apply_k<true><<<dim3(64,16), 256, 0, stream>>>(P, st1, gn1_g + i*256, gn1_b + i*256, bufA);
    q_k<<<16384, 256, 0, stream>>>(bufA, qkv_w + i*513*256, qkv_b + i*513, qbuf);
    gemm_k<1,256><<<dim3(32,4,16), 256, 0, stream>>>(w_qkv + (i*513+1)*256, bufA, 512,
        qkv_b + i*513 + 1, nullptr, bufB, nullptr, nullptr, nullptr, nullptr, nullptr, nullptr);
    softmax_k<<<64, 256, 0, stream>>>(qbuf, scor, ctxs);
    ctx_k<<<dim3(64,4), 256, 0, stream>>>(bufB, scor, ctxs);
    attn_in_k<<<16384, 256, 0, stream>>>(bufB, ctxs, bufA);
    // out proj: P += (unpermute), stats -> gn2 site
    gemm_k<5,256><<<dim3(32,2,16), 256, 0, stream>>>(w_out + i*65536, bufA, 256,
        out_b + i*256, P, nullptr, nullptr, nullptr, nullptr, nullptr, nullptr,
        stats + (i == 0 ? 1 : 3)*32);
    float* st2 = stats + (i == 0 ? 1 : 3)*32;
    gn_apply_k<false><<<dim3(64,16), 256, 0, stream>>>(P, st2, gn2_g + i*256, gn2_b + i*256, bufA);
    gemm_k<3,256><<<dim3(32,4,16), 256, 0, stream>>>(w_f1 + i*131072, bufA, 512,
        ffn1_b + i*512, nullptr, bufB, nullptr, nullptr, nullptr, nullptr, nullptr, nullptr);
    // ffn2: P += , stats -> next gn1 site (i=0) or gnf site (i=1)
    gemm_k<2,512><<<dim3(32,2,16), 256, 0, stream>>>(w_f2 + i*131072, bufB, 256,
        ffn2_b + i*256, P, nullptr, nullptr, nullptr, nullptr, nullptr, nullptr,
        stats + (i == 0 ? 2 : 4)*32);
  }

  gn_apply_k<false><<<dim3(64,16), 256, 0, stream>>>(P, stats + 4*32, gnf_g, gnf_b, bufA);
  gemm_k<4,256><<<dim3(32,2,16), 256, 0, stream>>>(w_pj, bufA, 256, nullptr,
      nullptr, nullptr, out, pbn_g, pbn_b, pbn_m, pbn_v, nullptr);

  (void)in_sizes; (void)n_in; (void)out_size; (void)ws_size;
}

// Round 5
// 634.702 us; speedup vs baseline: 1.5329x; 1.2092x over previous
//
#include <hip/hip_runtime.h>
#include <hip/hip_bf16.h>
#include <stdint.h>

// MobileViTBlockV2: B=16, C=256, H=W=64, D=256, F=512, L=2, patch 2x2.
// R5: vectorized dwconv (1 block/plane), vectorized transpose, residual P in
// bf16 (halves RMW + gn_apply traffic), 16B epilogue granules, single cvt
// launch. GEMM core unchanged from R4 (W-as-A, BK=64 XOR-swizzled DMA).

#define B_    16
#define C_    256
#define D_    256
#define NPIX  4096
#define NE_PB 1048576   // D_*NPIX elements per batch for GN

typedef __attribute__((ext_vector_type(8))) short  short8;
typedef __attribute__((ext_vector_type(4))) short  short4v;
typedef __attribute__((ext_vector_type(4))) float  f32x4;
typedef __attribute__((ext_vector_type(2))) float  f32x2;

__device__ __forceinline__ float b2f(short s){
  return __uint_as_float(((unsigned)(unsigned short)s) << 16);
}
__device__ __forceinline__ short f2b(float f){
  unsigned u = __float_as_uint(f);
  return (short)((u + 0x7fffu + ((u >> 16) & 1u)) >> 16);  // RNE
}
__device__ __forceinline__ float silu_f(float x){ return x / (1.f + expf(-x)); }

__device__ __forceinline__ void gld16(const short* g, short* l){
  __builtin_amdgcn_global_load_lds(
      (const __attribute__((address_space(1))) void*)g,
      (__attribute__((address_space(3))) void*)l, 16, 0, 0);
}

// pixel -> parity-permuted index: pi = parity*1024 + (h/2)*32 + (w/2)
__device__ __forceinline__ int pix2pi(int pix){
  int h = pix >> 6, w = pix & 63;
  return ((h & 1)*2 + (w & 1))*1024 + (h >> 1)*32 + (w >> 1);
}
__device__ __forceinline__ int pi2pix(int n){
  int p = n >> 10, idx = n & 1023;
  int h = ((idx >> 5) << 1) | (p >> 1);
  int w = ((idx & 31) << 1) | (p & 1);
  return h*64 + w;
}

// ---------- all weight casts + stats zero in ONE launch ----------
__global__ void cvt6_k(const float* __restrict__ s0, const float* __restrict__ s1,
                       const float* __restrict__ s2, const float* __restrict__ s3,
                       const float* __restrict__ s4, const float* __restrict__ s5,
                       short* __restrict__ dst, float* __restrict__ stats){
  const int i = blockIdx.x*256 + threadIdx.x;
  if (blockIdx.x == 0 && threadIdx.x < 160) stats[threadIdx.x] = 0.f;
  if (i >= 1049088) return;
  float v;
  if      (i <  65536)  v = s0[i];
  else if (i < 328192)  v = s1[i -  65536];
  else if (i < 459264)  v = s2[i - 328192];
  else if (i < 721408)  v = s3[i - 459264];
  else if (i < 983552)  v = s4[i - 721408];
  else                  v = s5[i - 983552];
  dst[i] = f2b(v);
}

// ---------- dwconv3x3 + BN + SiLU: one block per (b,c) plane ----------
__global__ __launch_bounds__(256)
void dwconv_k(const float* __restrict__ X, const float* __restrict__ W,
              const float* __restrict__ G, const float* __restrict__ Bb,
              const float* __restrict__ Mn, const float* __restrict__ Vr,
              short* __restrict__ O){
  const int c = blockIdx.x, b = blockIdx.y;
  const int t = threadIdx.x;
  __shared__ float xs[66][68];
  // halo zero
  if (t < 132){ int r = (t >= 66) ? 65 : 0; int cc = (t >= 66) ? t-66 : t; xs[r][cc] = 0.f; }
  if (t < 128){ int r = 1 + (t & 63); int cc = (t >> 6) ? 65 : 0; xs[r][cc] = 0.f; }
  const float* xp = X + ((size_t)(b*C_ + c)) * NPIX;
#pragma unroll
  for (int it = 0; it < 4; ++it){
    const int idx = it*256 + t;
    const int row = idx >> 4, cq = idx & 15;
    f32x4 v = *(const f32x4*)&xp[row*64 + cq*4];
    xs[row+1][cq*4+1] = v.x; xs[row+1][cq*4+2] = v.y;
    xs[row+1][cq*4+3] = v.z; xs[row+1][cq*4+4] = v.w;
  }
  float wgt[9];
#pragma unroll
  for (int j = 0; j < 9; ++j) wgt[j] = W[c*9 + j];
  const float scale = G[c] * rsqrtf(Vr[c] + 1e-5f);
  const float mu = Mn[c], bb = Bb[c];
  __syncthreads();
  const int tr = t >> 4, tc = t & 15;
  float win[6][6];
#pragma unroll
  for (int dr = 0; dr < 6; ++dr){
    f32x4 a = *(const f32x4*)&xs[tr*4+dr][tc*4];
    f32x2 bq = *(const f32x2*)&xs[tr*4+dr][tc*4+4];
    win[dr][0] = a.x; win[dr][1] = a.y; win[dr][2] = a.z; win[dr][3] = a.w;
    win[dr][4] = bq.x; win[dr][5] = bq.y;
  }
  short* op = O + ((size_t)(b*C_ + c)) * NPIX;
#pragma unroll
  for (int jr = 0; jr < 4; ++jr){
    short4v o;
#pragma unroll
    for (int jc = 0; jc < 4; ++jc){
      float s = 0.f;
#pragma unroll
      for (int dh = 0; dh < 3; ++dh)
#pragma unroll
        for (int dw = 0; dw < 3; ++dw)
          s += win[jr+dh][jc+dw] * wgt[dh*3+dw];
      float y = (s - mu) * scale + bb;
      o[jc] = f2b(silu_f(y));
    }
    *(short4v*)&op[(tr*4+jr)*64 + tc*4] = o;
  }
}

// ---------- (b,c,s) -> (b,s,c) bf16 transpose, 64x64 tiles, vector both sides ----------
__global__ void transpose_k(const short* __restrict__ I, short* __restrict__ O){
  const int s0 = blockIdx.x*64, c0 = blockIdx.y*64, b = blockIdx.z;
  const int t = threadIdx.x;
  __shared__ short tile[64][68];   // [s_local][c_local]
  const int hi = t >> 4, lo = t & 15;
#pragma unroll
  for (int cy = 0; cy < 4; ++cy){
    const int cl = cy*16 + hi;
    short4v v = *(const short4v*)&I[((size_t)(b*C_ + c0 + cl))*NPIX + s0 + lo*4];
    tile[lo*4+0][cl] = v.x; tile[lo*4+1][cl] = v.y;
    tile[lo*4+2][cl] = v.z; tile[lo*4+3][cl] = v.w;
  }
  __syncthreads();
#pragma unroll
  for (int py = 0; py < 4; ++py){
    const int pl = py*16 + hi;
    short4v v = *(const short4v*)&tile[pl][lo*4];
    *(short4v*)&O[((size_t)(b*NPIX + s0 + pl))*C_ + c0 + lo*4] = v;
  }
}

// ---------- MFMA bf16 GEMM: D[pix][chan] = sum_k X[pix][k]*Wt[chan][k] ----------
// Tile 128 pix x 128 chan, BK=64. W is the MFMA A operand (chan on reg axis).
// EPI: 0 = P(bf16)=acc (+stats); 1 = bf16 Obf = acc+bias;
// 2 = P += acc+bias (+stats); 3 = bf16 Obf = silu(acc+bias);
// 4 = f32 NCHW Of32 = BN(acc); 5 = P += acc+bias at pi2pix(row) (+stats)
template<int EPI, int K>
__global__ __launch_bounds__(256, 3)
void gemm_k(const short* __restrict__ Wt, const short* __restrict__ X,
            const int M,
            const float* __restrict__ bias,
            short* __restrict__ P,
            short* __restrict__ Obf,
            float* __restrict__ Of32,
            const float* __restrict__ bng, const float* __restrict__ bnb,
            const float* __restrict__ bnm, const float* __restrict__ bnv,
            float* __restrict__ st)
{
  constexpr int S = K / 64;
  const int nt = blockIdx.x;          // pixel tile (128)
  const int ct = blockIdx.y;          // chan tile (128)
  const int b  = blockIdx.z;
  const int tid = threadIdx.x;
  const int ln = tid & 63, wv = tid >> 6;
  const int wx = wv & 1;              // chan half (64)
  const int wy = wv >> 1;             // pixel half (64)
  const int lr = ln & 15, lq = ln >> 4;
  const int rl = ln >> 3, sp = ln & 7;
  const int sw = sp ^ rl;             // staged k-seg (XOR swizzle)

  __shared__ __align__(16) char smem[33824];
  short* As = (short*)smem;            // W tile: 128 chan rows x 64 k (16 KB)
  short* Xs = (short*)(smem + 16384);  // X tile: 128 pix rows x 64 k (16 KB)
  float* CT = (float*)smem;            // epilogue restage (64x132 f32)
  float* red = (float*)(smem + 33792); // 8 floats

  const short* Wp = Wt + (size_t)(ct*128)*K;
  const short* Xp = X + ((size_t)b*NPIX + (size_t)nt*128) * K;

  const short* gw[4]; const short* gx[4]; short* lw[4]; short* lx[4];
#pragma unroll
  for (int j = 0; j < 4; ++j){
    const int row = 32*wv + 8*j + rl;
    gw[j] = Wp + (size_t)row*K + sw*8;
    gx[j] = Xp + (size_t)row*K + sw*8;
    lw[j] = As + (4*wv + j)*512;
    lx[j] = Xs + (4*wv + j)*512;
  }

  f32x4 acc[4][4];
#pragma unroll
  for (int r = 0; r < 4; ++r)
#pragma unroll
    for (int c = 0; c < 4; ++c) acc[r][c] = (f32x4){0.f,0.f,0.f,0.f};

  for (int stp = 0; stp < S; ++stp){
    if (stp) __syncthreads();
#pragma unroll
    for (int j = 0; j < 4; ++j) gld16(gw[j] + stp*64, lw[j]);
#pragma unroll
    for (int j = 0; j < 4; ++j) gld16(gx[j] + stp*64, lx[j]);
    __syncthreads();
#pragma unroll
    for (int kk = 0; kk < 2; ++kk){
      const int seg = ((kk*4 + lq) ^ (lr & 7)) * 16;   // byte offset in 128B row
      short8 aw[4], bx[4];
#pragma unroll
      for (int r = 0; r < 4; ++r)
        aw[r] = *(const short8*)((const char*)As + (wx*64 + r*16 + lr)*128 + seg);
#pragma unroll
      for (int c = 0; c < 4; ++c)
        bx[c] = *(const short8*)((const char*)Xs + (wy*64 + c*16 + lr)*128 + seg);
#pragma unroll
      for (int r = 0; r < 4; ++r)
#pragma unroll
        for (int c = 0; c < 4; ++c)
          acc[r][c] = __builtin_amdgcn_mfma_f32_16x16x32_bf16(aw[r], bx[c], acc[r][c], 0, 0, 0);
    }
  }
  // acc[r][c]: chan = ct*128 + wx*64 + r*16 + lq*4 + reg ; pix = nt*128 + wy*64 + c*16 + lr

  const int ch8 = (tid & 15) * 8;      // store-phase chan offset within 128
  f32x4 bv0 = (f32x4){0.f,0.f,0.f,0.f}, bv1 = bv0;
  if constexpr (EPI == 1 || EPI == 2 || EPI == 3 || EPI == 5){
    bv0 = *(const f32x4*)&bias[ct*128 + ch8];
    bv1 = *(const f32x4*)&bias[ct*128 + ch8 + 4];
  }

  float sm = 0.f, ss = 0.f;

  if constexpr (EPI != 4){
    // 2 passes over pixel halves; CT[pixL 0..63][chan 0..127], stride 132
#pragma unroll
    for (int p = 0; p < 2; ++p){
      __syncthreads();
      if (wy == p){
#pragma unroll
        for (int r = 0; r < 4; ++r)
#pragma unroll
          for (int c = 0; c < 4; ++c)
            *(f32x4*)&CT[(c*16 + lr)*132 + wx*64 + r*16 + lq*4] = acc[r][c];
      }
      __syncthreads();
#pragma unroll
      for (int it = 0; it < 4; ++it){
        const int pixL = it*16 + (tid >> 4);
        f32x4 v0 = *(const f32x4*)&CT[pixL*132 + ch8];
        f32x4 v1 = *(const f32x4*)&CT[pixL*132 + ch8 + 4];
        v0.x += bv0.x; v0.y += bv0.y; v0.z += bv0.z; v0.w += bv0.w;
        v1.x += bv1.x; v1.y += bv1.y; v1.z += bv1.z; v1.w += bv1.w;
        int pixg = nt*128 + p*64 + pixL;
        if constexpr (EPI == 5) pixg = pi2pix(pixg);
        const size_t rowb = (size_t)b*NPIX + pixg;
        if constexpr (EPI == 0){
          short8 o;
          o[0]=f2b(v0.x); o[1]=f2b(v0.y); o[2]=f2b(v0.z); o[3]=f2b(v0.w);
          o[4]=f2b(v1.x); o[5]=f2b(v1.y); o[6]=f2b(v1.z); o[7]=f2b(v1.w);
          *(short8*)&P[rowb*256 + ct*128 + ch8] = o;
          sm += v0.x+v0.y+v0.z+v0.w + v1.x+v1.y+v1.z+v1.w;
          ss += v0.x*v0.x+v0.y*v0.y+v0.z*v0.z+v0.w*v0.w
              + v1.x*v1.x+v1.y*v1.y+v1.z*v1.z+v1.w*v1.w;
        } else if constexpr (EPI == 2 || EPI == 5){
          short* pp = &P[rowb*256 + ct*128 + ch8];
          short8 old = *(const short8*)pp;
          float n0 = b2f(old[0])+v0.x, n1 = b2f(old[1])+v0.y;
          float n2 = b2f(old[2])+v0.z, n3 = b2f(old[3])+v0.w;
          float n4 = b2f(old[4])+v1.x, n5 = b2f(old[5])+v1.y;
          float n6 = b2f(old[6])+v1.z, n7 = b2f(old[7])+v1.w;
          short8 o;
          o[0]=f2b(n0); o[1]=f2b(n1); o[2]=f2b(n2); o[3]=f2b(n3);
          o[4]=f2b(n4); o[5]=f2b(n5); o[6]=f2b(n6); o[7]=f2b(n7);
          *(short8*)pp = o;
          sm += n0+n1+n2+n3+n4+n5+n6+n7;
          ss += n0*n0+n1*n1+n2*n2+n3*n3+n4*n4+n5*n5+n6*n6+n7*n7;
        } else if constexpr (EPI == 1){
          short8 o;
          o[0]=f2b(v0.x); o[1]=f2b(v0.y); o[2]=f2b(v0.z); o[3]=f2b(v0.w);
          o[4]=f2b(v1.x); o[5]=f2b(v1.y); o[6]=f2b(v1.z); o[7]=f2b(v1.w);
          *(short8*)&Obf[rowb*(size_t)M + ct*128 + ch8] = o;
        } else {  // EPI == 3
          short8 o;
          o[0]=f2b(silu_f(v0.x)); o[1]=f2b(silu_f(v0.y));
          o[2]=f2b(silu_f(v0.z)); o[3]=f2b(silu_f(v0.w));
          o[4]=f2b(silu_f(v1.x)); o[5]=f2b(silu_f(v1.y));
          o[6]=f2b(silu_f(v1.z)); o[7]=f2b(silu_f(v1.w));
          *(short8*)&Obf[rowb*(size_t)M + ct*128 + ch8] = o;
        }
      }
    }
    if constexpr (EPI == 0 || EPI == 2 || EPI == 5){
#pragma unroll
      for (int o = 32; o > 0; o >>= 1){ sm += __shfl_down(sm, o); ss += __shfl_down(ss, o); }
      if (ln == 0){ red[wv*2] = sm; red[wv*2+1] = ss; }
      __syncthreads();
      if (tid == 0){
        atomicAdd(&st[b*2+0], red[0]+red[2]+red[4]+red[6]);
        atomicAdd(&st[b*2+1], red[1]+red[3]+red[5]+red[7]);
      }
    }
  } else {
    // EPI 4: BN -> f32 NCHW; 2 passes over chan halves; CT[chanL 0..63][pix 0..127]
#pragma unroll
    for (int p = 0; p < 2; ++p){
      __syncthreads();
      if (wx == p){
#pragma unroll
        for (int r = 0; r < 4; ++r)
#pragma unroll
          for (int c = 0; c < 4; ++c){
            const int pixL = wy*64 + c*16 + lr;
#pragma unroll
            for (int j = 0; j < 4; ++j)
              CT[(r*16 + lq*4 + j)*132 + pixL] = acc[r][c][j];
          }
      }
      __syncthreads();
#pragma unroll
      for (int it = 0; it < 8; ++it){
        const int idx = it*256 + tid;
        const int chL = idx >> 5, pq = (idx & 31)*4;
        const int chan = ct*128 + p*64 + chL;
        f32x4 v = *(const f32x4*)&CT[chL*132 + pq];
        const float sc = bng[chan] * rsqrtf(bnv[chan] + 1e-5f);
        const float mu = bnm[chan], bb = bnb[chan];
        f32x4 o;
        o.x = (v.x - mu)*sc + bb; o.y = (v.y - mu)*sc + bb;
        o.z = (v.z - mu)*sc + bb; o.w = (v.w - mu)*sc + bb;
        *(f32x4*)&Of32[((size_t)(b*C_ + chan))*NPIX + (size_t)nt*128 + pq] = o;
      }
    }
  }
}

// ---------- GN apply (stats pre-computed by GEMM epilogues), bf16 P ----------
template<bool PERM>
__global__ void gn_apply_k(const short* __restrict__ P, const float* __restrict__ st,
                           const float* __restrict__ G, const float* __restrict__ Bb,
                           short* __restrict__ U){
  const int b = blockIdx.y;
  const float mean = st[b*2]   * (1.f/NE_PB);
  const float var  = st[b*2+1] * (1.f/NE_PB) - mean*mean;
  const float inv  = rsqrtf(var + 1e-5f);
  const int t = threadIdx.x;
  const int c0 = (t*8) & 255;
  const f32x4 g0 = *(const f32x4*)&G[c0],  g1 = *(const f32x4*)&G[c0+4];
  const f32x4 b0 = *(const f32x4*)&Bb[c0], b1 = *(const f32x4*)&Bb[c0+4];
#pragma unroll
  for (int i = 0; i < 16; ++i){
    const int e = blockIdx.x*32768 + t*8 + i*2048;
    short8 pv = *(const short8*)&P[(size_t)b*NE_PB + e];
    short8 o;
    o[0] = f2b((b2f(pv[0]) - mean)*inv*g0.x + b0.x);
    o[1] = f2b((b2f(pv[1]) - mean)*inv*g0.y + b0.y);
    o[2] = f2b((b2f(pv[2]) - mean)*inv*g0.z + b0.z);
    o[3] = f2b((b2f(pv[3]) - mean)*inv*g0.w + b0.w);
    o[4] = f2b((b2f(pv[4]) - mean)*inv*g1.x + b1.x);
    o[5] = f2b((b2f(pv[5]) - mean)*inv*g1.y + b1.y);
    o[6] = f2b((b2f(pv[6]) - mean)*inv*g1.z + b1.z);
    o[7] = f2b((b2f(pv[7]) - mean)*inv*g1.w + b1.w);
    if constexpr (PERM){
      const int pix = e >> 8;
      *(short8*)&U[((size_t)b*NPIX + pix2pi(pix))*256 + c0] = o;
    } else {
      *(short8*)&U[(size_t)b*NE_PB + e] = o;
    }
  }
}

// ---------- q = Wq . u + qb  (one wave per pixel row; rows in pi-order) ----------
__global__ void q_k(const short* __restrict__ U, const float* __restrict__ Wq,
                    const float* __restrict__ Qb, float* __restrict__ Q){
  const int lane = threadIdx.x & 63;
  const int pix = (blockIdx.x*256 + threadIdx.x) >> 6;
  short4v u4 = *(const short4v*)&U[(size_t)pix*256 + lane*4];
  f32x4  w4 = *(const f32x4*)&Wq[lane*4];
  float s = b2f(u4.x)*w4.x + b2f(u4.y)*w4.y + b2f(u4.z)*w4.z + b2f(u4.w)*w4.w;
#pragma unroll
  for (int o = 32; o > 0; o >>= 1) s += __shfl_down(s, o);
  if (lane == 0) Q[pix] = s + Qb[0];
}

// ---------- softmax over 1024 contiguous pi-pixels; also zeroes ctx accum ----------
__global__ void softmax_k(const float* __restrict__ Q, float* __restrict__ S,
                          float* __restrict__ CT){
  const int bp = blockIdx.x;
  const int t = threadIdx.x;
  CT[bp*256 + t] = 0.f;
  float vals[4];
  float mx = -1e30f;
#pragma unroll
  for (int j = 0; j < 4; ++j){
    vals[j] = Q[bp*1024 + t + j*256];
    mx = fmaxf(mx, vals[j]);
  }
  __shared__ float red[4];
  const int lane = t & 63, wv = t >> 6;
#pragma unroll
  for (int o = 32; o > 0; o >>= 1) mx = fmaxf(mx, __shfl_down(mx, o));
  if (lane == 0) red[wv] = mx;
  __syncthreads();
  mx = fmaxf(fmaxf(red[0], red[1]), fmaxf(red[2], red[3]));
  __syncthreads();
  float sum = 0.f;
#pragma unroll
  for (int j = 0; j < 4; ++j){ vals[j] = expf(vals[j] - mx); sum += vals[j]; }
#pragma unroll
  for (int o = 32; o > 0; o >>= 1) sum += __shfl_down(sum, o);
  if (lane == 0) red[wv] = sum;
  __syncthreads();
  sum = red[0] + red[1] + red[2] + red[3];
  const float r = 1.f / sum;
#pragma unroll
  for (int j = 0; j < 4; ++j) S[bp*1024 + t + j*256] = vals[j]*r;
}

// ---------- ctx[bp][c] = sum_n k[bp*1024+n][c] * s[bp][n]  (coalesced, atomics) ----------
__global__ void ctx_k(const short* __restrict__ KV, const float* __restrict__ S,
                      float* __restrict__ CT){
  const int bp = blockIdx.x, ch = blockIdx.y;
  const int ln = threadIdx.x & 63, wv = threadIdx.x >> 6;
  const int j0 = ch*256 + wv*64;
  f32x4 acc = (f32x4){0.f,0.f,0.f,0.f};
  for (int jj = 0; jj < 64; jj += 4){
    f32x4 s4 = *(const f32x4*)&S[bp*1024 + j0 + jj];
#pragma unroll
    for (int u = 0; u < 4; ++u){
      short4v kv = *(const short4v*)&KV[((size_t)bp*1024 + j0 + jj + u)*512 + ln*4];
      const float s = s4[u];
      acc.x += b2f(kv.x)*s; acc.y += b2f(kv.y)*s;
      acc.z += b2f(kv.z)*s; acc.w += b2f(kv.w)*s;
    }
  }
  atomicAdd(&CT[bp*256 + ln*4 + 0], acc.x);
  atomicAdd(&CT[bp*256 + ln*4 + 1], acc.y);
  atomicAdd(&CT[bp*256 + ln*4 + 2], acc.z);
  atomicAdd(&CT[bp*256 + ln*4 + 3], acc.w);
}

// ---------- attn input: relu(v) * ctx[parity]  (all pi-ordered) ----------
__global__ void attn_in_k(const short* __restrict__ KV, const float* __restrict__ CT,
                          short* __restrict__ O){
  const size_t vid = (size_t)blockIdx.x*256 + threadIdx.x;
  const int c4 = (int)(vid & 63);
  const size_t r = vid >> 6;
  const int bp = (int)(r >> 10);
  short4v v4 = *(const short4v*)&KV[r*512 + 256 + c4*4];
  f32x4  cx = *(const f32x4*)&CT[bp*256 + c4*4];
  short4v o;
  o.x = f2b(fmaxf(b2f(v4.x), 0.f)*cx.x);
  o.y = f2b(fmaxf(b2f(v4.y), 0.f)*cx.y);
  o.z = f2b(fmaxf(b2f(v4.z), 0.f)*cx.z);
  o.w = f2b(fmaxf(b2f(v4.w), 0.f)*cx.w);
  *(short4v*)&O[r*256 + c4*4] = o;
}

extern "C" void kernel_launch(void* const* d_in, const int* in_sizes, int n_in,
                              void* d_out, int out_size, void* d_ws, size_t ws_size,
                              hipStream_t stream){
  const float* x      = (const float*)d_in[0];
  const float* dw_w   = (const float*)d_in[1];
  const float* dw_g   = (const float*)d_in[2];
  const float* dw_b   = (const float*)d_in[3];
  const float* dw_m   = (const float*)d_in[4];
  const float* dw_v   = (const float*)d_in[5];
  const float* pw_w   = (const float*)d_in[6];
  const float* gn1_g  = (const float*)d_in[7];
  const float* gn1_b  = (const float*)d_in[8];
  const float* qkv_w  = (const float*)d_in[9];
  const float* qkv_b  = (const float*)d_in[10];
  const float* out_w  = (const float*)d_in[11];
  const float* out_b  = (const float*)d_in[12];
  const float* gn2_g  = (const float*)d_in[13];
  const float* gn2_b  = (const float*)d_in[14];
  const float* ffn1_w = (const float*)d_in[15];
  const float* ffn1_b = (const float*)d_in[16];
  const float* ffn2_w = (const float*)d_in[17];
  const float* ffn2_b = (const float*)d_in[18];
  const float* gnf_g  = (const float*)d_in[19];
  const float* gnf_b  = (const float*)d_in[20];
  const float* proj_w = (const float*)d_in[21];
  const float* pbn_g  = (const float*)d_in[22];
  const float* pbn_b  = (const float*)d_in[23];
  const float* pbn_m  = (const float*)d_in[24];
  const float* pbn_v  = (const float*)d_in[25];
  float* out = (float*)d_out;

  uint8_t* w8 = (uint8_t*)d_ws;
  short* P     = (short*)(w8);                  // bf16 residual, 32 MiB
  short* bufA  = (short*)(w8 + 33554432);       // bf16 (B,4096,256), 32 MiB
  short* bufB  = (short*)(w8 + 67108864);       // bf16 (B,4096,512), 64 MiB
  short* wbase = (short*)(w8 + 134217728);      // all weights bf16, contiguous
  short* w_pw  = wbase;
  short* w_qkv = wbase + 65536;
  short* w_out = wbase + 328192;
  short* w_f1  = wbase + 459264;
  short* w_f2  = wbase + 721408;
  short* w_pj  = wbase + 983552;
  float* qbuf  = (float*)(w8 + 136315904);      // (B*4096)
  float* scor  = (float*)(w8 + 136578048);      // (64,1024)
  float* ctxs  = (float*)(w8 + 136840192);      // (64,256)
  float* stats = (float*)(w8 + 136905728);      // 5 sites x 16 x 2

  cvt6_k<<<4098, 256, 0, stream>>>(pw_w, qkv_w, out_w, ffn1_w, ffn2_w, proj_w,
                                   wbase, stats);

  dwconv_k<<<dim3(256,16), 256, 0, stream>>>(x, dw_w, dw_g, dw_b, dw_m, dw_v, bufB);
  transpose_k<<<dim3(64,4,16), 256, 0, stream>>>(bufB, bufA);

  // pw conv -> P (stats site 0 = gn1 layer 0)
  gemm_k<0,256><<<dim3(32,2,16), 256, 0, stream>>>(w_pw, bufA, 256, nullptr, P,
      nullptr, nullptr, nullptr, nullptr, nullptr, nullptr, stats + 0);

  for (int i = 0; i < 2; ++i){
    float* st1 = stats + (i == 0 ? 0 : 2*32);            // gn1 site
    gn_apply_k<true><<<dim3(32,16), 256, 0, stream>>>(P, st1, gn1_g + i*256, gn1_b + i*256, bufA);
    q_k<<<16384, 256, 0, stream>>>(bufA, qkv_w + i*513*256, qkv_b + i*513, qbuf);
    gemm_k<1,256><<<dim3(32,4,16), 256, 0, stream>>>(w_qkv + (i*513+1)*256, bufA, 512,
        qkv_b + i*513 + 1, nullptr, bufB, nullptr, nullptr, nullptr, nullptr, nullptr, nullptr);
    softmax_k<<<64, 256, 0, stream>>>(qbuf, scor, ctxs);
    ctx_k<<<dim3(64,4), 256, 0, stream>>>(bufB, scor, ctxs);
    attn_in_k<<<16384, 256, 0, stream>>>(bufB, ctxs, bufA);
    // out proj: P += (unpermute), stats -> gn2 site
    gemm_k<5,256><<<dim3(32,2,16), 256, 0, stream>>>(w_out + i*65536, bufA, 256,
        out_b + i*256, P, nullptr, nullptr, nullptr, nullptr, nullptr, nullptr,
        stats + (i == 0 ? 1 : 3)*32);
    float* st2 = stats + (i == 0 ? 1 : 3)*32;
    gn_apply_k<false><<<dim3(32,16), 256, 0, stream>>>(P, st2, gn2_g + i*256, gn2_b + i*256, bufA);
    gemm_k<3,256><<<dim3(32,4,16), 256, 0, stream>>>(w_f1 + i*131072, bufA, 512,
        ffn1_b + i*512, nullptr, bufB, nullptr, nullptr, nullptr, nullptr, nullptr, nullptr);
    // ffn2: P += , stats -> next gn1 site (i=0) or gnf site (i=1)
    gemm_k<2,512><<<dim3(32,2,16), 256, 0, stream>>>(w_f2 + i*131072, bufB, 256,
        ffn2_b + i*256, P, nullptr, nullptr, nullptr, nullptr, nullptr, nullptr,
        stats + (i == 0 ? 2 : 4)*32);
  }

  gn_apply_k<false><<<dim3(32,16), 256, 0, stream>>>(P, stats + 4*32, gnf_g, gnf_b, bufA);
  gemm_k<4,256><<<dim3(32,2,16), 256, 0, stream>>>(w_pj, bufA, 256, nullptr,
      nullptr, nullptr, out, pbn_g, pbn_b, pbn_m, pbn_v, nullptr);

  (void)in_sizes; (void)n_in; (void)out_size; (void)ws_size;
}